// Round 6
// baseline (1068.052 us; speedup 1.0000x reference)
//
#include <hip/hip_runtime.h>

typedef unsigned int uint;
typedef unsigned short ushort;

using bf16x8 = __attribute__((ext_vector_type(8))) short;
using f32x4  = __attribute__((ext_vector_type(4))) float;

__device__ __forceinline__ float lrelu(float v) { return v > 0.f ? v : 0.01f * v; }
__device__ __forceinline__ float b2f(ushort u) { return __uint_as_float((uint)u << 16); }
__device__ __forceinline__ ushort f2b(float f) {
  uint u = __float_as_uint(f);
  u += 0x7fffu + ((u >> 16) & 1u);   // round-to-nearest-even
  return (ushort)(u >> 16);
}

// HW_REG_XCC_ID = hwreg id 20 (gfx940+); size 32, offset 0 -> encoding (31<<11)|20.
__device__ __forceinline__ uint get_xcc() {
  return (uint)__builtin_amdgcn_s_getreg((31 << 11) | 20) & 7u;
}

#define CSR_B 256          // blocks in coarse passes
#define BKT_SHIFT 10       // 1024 dst nodes per bucket
#define MAX_NB 64          // max buckets (N <= 65536)

// y buffers are CHANNEL-CHUNKED into 4 chunks of 32 ch: y[chunk][node][32].
// Row = 64 B = one cache line; chunk slab = N*64 B = 3.2 MB < 4 MiB per-XCD L2.
// agg pins chunk to XCD via HW_REG_XCC_ID + per-chunk work-stealing counters.

// ---------------------------------------------------------------------------
// MFMA GEMM: C[N,128] = A[N,K] @ W[K,128] + bias, bf16 in / fp32 acc.
// A given as up to 4 chunked y-buffer pointers (K = 128*chunks).
// Wt pre-transposed: Wt[n][k] bf16.
// MODE 0: h = lrelu(acc+b); yout = bf16(lrelu(h))           (readin)
// MODE 1: h += acc+b; if yout: yout = bf16(act? lrelu(h):h) (layer taps, fused cast)
// MODE 2: h = acc+b                                          (readout)
// ---------------------------------------------------------------------------
template <int MODE, int K>
__global__ __launch_bounds__(256) void gemm_mfma(
    const ushort* __restrict__ A0, const ushort* __restrict__ A1,
    const ushort* __restrict__ A2, const ushort* __restrict__ A3,
    const ushort* __restrict__ Wt, const float* __restrict__ bias,
    float* __restrict__ h, ushort* __restrict__ yout, int do_act, int N) {
  __shared__ ushort As[64][40];    // [m][k], stride 40 (16B-aligned, 2-way-free banks)
  __shared__ ushort Bs[128][40];   // [n][k]
  const int tid = threadIdx.x;
  const int lane = tid & 63;
  const int wave = tid >> 6;
  const int g = lane >> 4;         // k-quad
  const int mr = lane & 15;
  const int wr = wave >> 1;        // row half
  const int wc = wave & 1;         // col half
  const int row0 = blockIdx.x * 64;

  const ushort* Ap[4] = {A0, A1, A2, A3};

  f32x4 acc[2][4];
#pragma unroll
  for (int i = 0; i < 2; i++)
#pragma unroll
    for (int j = 0; j < 4; j++) acc[i][j] = (f32x4){0.f, 0.f, 0.f, 0.f};

#pragma unroll 4
  for (int kc = 0; kc < K; kc += 32) {
    {  // stage A: 64 rows x 32 k (one uint4 per thread), 4x32-chunked layout
      int m = tid >> 2, q = tid & 3;
      int r = row0 + m;
      if (r >= N) r = N - 1;
      int kg = kc + q * 8;
      const ushort* ap = Ap[kg >> 7] + ((size_t)((kg >> 5) & 3)) * N * 32 +
                         (size_t)r * 32 + (kg & 31);
      *(uint4*)&As[m][q * 8] = *(const uint4*)ap;
    }
#pragma unroll
    for (int t = 0; t < 2; t++) {  // stage B: 128 n x 32 k
      int slot = tid + t * 256;
      int n = slot >> 2, q = slot & 3;
      *(uint4*)&Bs[n][q * 8] = *(const uint4*)(Wt + (size_t)n * K + kc + q * 8);
    }
    __syncthreads();
    bf16x8 af[2], bf[4];
#pragma unroll
    for (int rt = 0; rt < 2; rt++) af[rt] = *(bf16x8*)&As[wr * 32 + rt * 16 + mr][g * 8];
#pragma unroll
    for (int ct = 0; ct < 4; ct++) bf[ct] = *(bf16x8*)&Bs[wc * 64 + ct * 16 + mr][g * 8];
#pragma unroll
    for (int rt = 0; rt < 2; rt++)
#pragma unroll
      for (int ct = 0; ct < 4; ct++)
        acc[rt][ct] = __builtin_amdgcn_mfma_f32_16x16x32_bf16(af[rt], bf[ct], acc[rt][ct], 0, 0, 0);
    __syncthreads();
  }

  // epilogue: C/D layout col=lane&15, row=(lane>>4)*4+reg
#pragma unroll
  for (int rt = 0; rt < 2; rt++) {
#pragma unroll
    for (int i = 0; i < 4; i++) {
      int R = row0 + wr * 32 + rt * 16 + g * 4 + i;
      if (R >= N) continue;
#pragma unroll
      for (int ct = 0; ct < 4; ct++) {
        int c = wc * 64 + ct * 16 + mr;       // chunk = c>>5, within = c&31
        float v = acc[rt][ct][i] + bias[c];
        size_t o = (size_t)R * 128 + c;
        size_t oy = (size_t)(c >> 5) * N * 32 + (size_t)R * 32 + (c & 31);
        if (MODE == 0) {
          float hv = lrelu(v);
          h[o] = hv;
          yout[oy] = f2b(lrelu(hv));
        } else if (MODE == 1) {
          float hv = h[o] + v;
          h[o] = hv;
          if (yout) yout[oy] = f2b(do_act ? lrelu(hv) : hv);
        } else {
          h[o] = v;
        }
      }
    }
  }
}

// ---------------- bf16 aggregation, XCD-pinned persistent kernel -------------
// chunk = XCC_ID&3 (hardware-read), tiles of 64 nodes grabbed from per-chunk
// atomic counters; falls over to other chunks when own chunk exhausted.
// 4 lanes x uint4 (16 B) per node = one 64 B line per edge-gather; 8-deep unroll.
__global__ __launch_bounds__(256) void agg_bf16(const ushort* __restrict__ yin,
                                                ushort* __restrict__ yout,
                                                const int* __restrict__ rowp,
                                                const ushort* __restrict__ esrc,
                                                int* __restrict__ cnt, int N) {
  __shared__ int s_tile;
  const int T = (N + 63) >> 6;   // tiles per chunk
  const int t = threadIdx.x;
  const int lane = t & 3;
  const int nsub = t >> 2;
  const uint mychunk = get_xcc() & 3u;

  for (int c = 0; c < 4; c++) {
    const int chunk = (int)((mychunk + c) & 3u);
    const ushort* yb = yin + (size_t)chunk * N * 32 + lane * 8;
    ushort* yo = yout + (size_t)chunk * N * 32 + lane * 8;
    while (true) {
      if (t == 0) s_tile = atomicAdd(&cnt[chunk], 1);
      __syncthreads();
      const int tile = s_tile;
      __syncthreads();
      if (tile >= T) break;
      const int node = tile * 64 + nsub;
      if (node < N) {
        const int beg = rowp[node], end = rowp[node + 1];
        float s[8] = {0.f, 0.f, 0.f, 0.f, 0.f, 0.f, 0.f, 0.f};
        int j = beg;
        for (; j + 8 <= end; j += 8) {
          union { uint4 v; ushort u[8]; } w[8];
#pragma unroll
          for (int u = 0; u < 8; u++) {
            int sn = esrc[j + u];
            w[u].v = *(const uint4*)(yb + (size_t)sn * 32);
          }
#pragma unroll
          for (int e = 0; e < 8; e++) {
            float a = 0.f;
#pragma unroll
            for (int u = 0; u < 8; u++) a += b2f(w[u].u[e]);
            s[e] += a;
          }
        }
        for (; j < end; j++) {
          int sn = esrc[j];
          union { uint4 v; ushort u[8]; } w;
          w.v = *(const uint4*)(yb + (size_t)sn * 32);
#pragma unroll
          for (int e = 0; e < 8; e++) s[e] += b2f(w.u[e]);
        }
        union { uint4 v; ushort u[8]; } o;
#pragma unroll
        for (int e = 0; e < 8; e++) o.u[e] = f2b(s[e]);
        *(uint4*)(yo + (size_t)node * 32) = o.v;
      }
    }
  }
}

// ---------------- fp32 [N][128] -> bf16 chunked y ----------------
__global__ __launch_bounds__(256) void cast_f2b(const float* __restrict__ in,
                                                ushort* __restrict__ out, int N) {
  int i = blockIdx.x * 256 + threadIdx.x;
  if (i >= N * 16) return;
  int node = i >> 4, sub = i & 15;           // 8 channels per thread
  float4 a = *(const float4*)(in + (size_t)node * 128 + sub * 8);
  float4 b = *(const float4*)(in + (size_t)node * 128 + sub * 8 + 4);
  float v[8] = {a.x, a.y, a.z, a.w, b.x, b.y, b.z, b.w};
  union { uint4 q; ushort u[8]; } o;
#pragma unroll
  for (int e = 0; e < 8; e++) o.u[e] = f2b(v[e]);
  int chunk = sub >> 2, off = (sub & 3) * 8;
  *(uint4*)(out + (size_t)chunk * N * 32 + (size_t)node * 32 + off) = o.q;
}

// ---------------- weight prep: cast + transpose + bias sums ------------------
__global__ __launch_bounds__(256) void prep_k(const float* __restrict__ w_in,
                                              const float* __restrict__ w_out,
                                              const float* __restrict__ taps_w,
                                              const float* __restrict__ taps_b,
                                              ushort* __restrict__ Wt_in,
                                              ushort* __restrict__ Wt_out,
                                              ushort* __restrict__ Wt_l0,
                                              ushort* __restrict__ Wt_l1,
                                              float* __restrict__ bsum) {
  int gid = blockIdx.x * 256 + threadIdx.x;
  if (gid < 16384) {
    int n = gid >> 7, k = gid & 127;
    Wt_in[gid] = f2b(w_in[k * 128 + n]);
  } else if (gid < 32768) {
    int i = gid - 16384;
    int n = i >> 7, k = i & 127;
    Wt_out[i] = f2b(w_out[k * 128 + n]);
  } else if (gid < 98304) {
    int i = gid - 32768;
    int n = i >> 9, k = i & 511;
    Wt_l0[i] = f2b(taps_w[(size_t)k * 128 + n]);
  } else if (gid < 163840) {
    int i = gid - 98304;
    int n = i >> 9, k = i & 511;
    Wt_l1[i] = f2b(taps_w[(size_t)(512 + k) * 128 + n]);
  } else if (gid < 164096) {
    int i = gid - 163840;
    int l = i >> 7, n = i & 127;
    float s = 0.f;
    for (int k = 0; k < 4; k++) s += taps_b[l * 512 + k * 128 + n];
    bsum[i] = s;
  }
}

// ---------------- CSR build: 2-level binned counting sort --------------------
__global__ __launch_bounds__(256) void chist_k(const int* __restrict__ dst,
                                               int* __restrict__ H, int E, int NB) {
  __shared__ int hh[MAX_NB];
  if (threadIdx.x < NB) hh[threadIdx.x] = 0;
  __syncthreads();
  int chunk = (E + gridDim.x - 1) / gridDim.x;
  int beg = blockIdx.x * chunk, end = min(E, beg + chunk);
  for (int e = beg + threadIdx.x; e < end; e += 256)
    atomicAdd(&hh[dst[e] >> BKT_SHIFT], 1);
  __syncthreads();
  if (threadIdx.x < NB) H[threadIdx.x * gridDim.x + blockIdx.x] = hh[threadIdx.x];
}

__global__ __launch_bounds__(256) void cscan_k(int* __restrict__ H, int M) {
  __shared__ int sm[256];
  int per = (M + 255) / 256;
  int b0 = threadIdx.x * per;
  int hi = min(M, b0 + per);
  int sum = 0;
  for (int i = b0; i < hi; i++) sum += H[i];
  sm[threadIdx.x] = sum;
  __syncthreads();
  int x = sum;
  for (int off = 1; off < 256; off <<= 1) {
    int tt = (threadIdx.x >= off) ? sm[threadIdx.x - off] : 0;
    __syncthreads();
    x += tt;
    sm[threadIdx.x] = x;
    __syncthreads();
  }
  int run = x - sum;  // exclusive
  for (int i = b0; i < hi; i++) {
    int v = H[i];
    H[i] = run;
    run += v;
  }
}

__global__ __launch_bounds__(256) void cscatter_k(const int* __restrict__ src,
                                                  const int* __restrict__ dst,
                                                  const int* __restrict__ H,
                                                  uint* __restrict__ packed,
                                                  int E, int NB) {
  __shared__ int cur[MAX_NB];
  int chunk = (E + gridDim.x - 1) / gridDim.x;
  int beg = blockIdx.x * chunk, end = min(E, beg + chunk);
  if (threadIdx.x < NB) cur[threadIdx.x] = H[threadIdx.x * gridDim.x + blockIdx.x];
  __syncthreads();
  for (int e = beg + threadIdx.x; e < end; e += 256) {
    int d = dst[e];
    int pos = atomicAdd(&cur[d >> BKT_SHIFT], 1);
    packed[pos] = ((uint)d << 16) | (uint)src[e];
  }
}

__global__ __launch_bounds__(256) void fsort_k(const uint* __restrict__ packed,
                                               const int* __restrict__ H,
                                               ushort* __restrict__ esrc,
                                               int* __restrict__ rowp,
                                               int N, int E, int NB) {
  __shared__ int hist[1 << BKT_SHIFT];
  __shared__ int cur[1 << BKT_SHIFT];
  __shared__ int sm[256];
  const int bkt = blockIdx.x;
  const int base = bkt << BKT_SHIFT;
  const int nb_nodes = min(1 << BKT_SHIFT, N - base);
  const int start = H[bkt * CSR_B];
  const int end = (bkt == NB - 1) ? E : H[(bkt + 1) * CSR_B];

  for (int i = threadIdx.x; i < (1 << BKT_SHIFT); i += 256) hist[i] = 0;
  __syncthreads();
  for (int e = start + threadIdx.x; e < end; e += 256)
    atomicAdd(&hist[(packed[e] >> 16) - base], 1);
  __syncthreads();

  int t4 = threadIdx.x * 4;
  int l0 = hist[t4], l1 = hist[t4 + 1], l2 = hist[t4 + 2], l3 = hist[t4 + 3];
  int ssum = l0 + l1 + l2 + l3;
  sm[threadIdx.x] = ssum;
  __syncthreads();
  int x = ssum;
  for (int off = 1; off < 256; off <<= 1) {
    int tt = (threadIdx.x >= off) ? sm[threadIdx.x - off] : 0;
    __syncthreads();
    x += tt;
    sm[threadIdx.x] = x;
    __syncthreads();
  }
  int c0 = start + x - ssum;
  int c1 = c0 + l0, c2 = c1 + l1, c3 = c2 + l2;
  cur[t4] = c0; cur[t4 + 1] = c1; cur[t4 + 2] = c2; cur[t4 + 3] = c3;
  if (t4 + 0 < nb_nodes) rowp[base + t4 + 0] = c0;
  if (t4 + 1 < nb_nodes) rowp[base + t4 + 1] = c1;
  if (t4 + 2 < nb_nodes) rowp[base + t4 + 2] = c2;
  if (t4 + 3 < nb_nodes) rowp[base + t4 + 3] = c3;
  __syncthreads();

  for (int e = start + threadIdx.x; e < end; e += 256) {
    uint p = packed[e];
    int pos = atomicAdd(&cur[(p >> 16) - base], 1);
    esrc[pos] = (ushort)(p & 0xffffu);
  }
  if (bkt == 0 && threadIdx.x == 0) rowp[N] = E;
}

// ---------------------------------------------------------------------------
extern "C" void kernel_launch(void* const* d_in, const int* in_sizes, int n_in,
                              void* d_out, int out_size, void* d_ws, size_t ws_size,
                              hipStream_t stream) {
  const float* x      = (const float*)d_in[0];
  const int*   ei     = (const int*)d_in[1];
  const float* w_in   = (const float*)d_in[2];
  const float* b_in   = (const float*)d_in[3];
  const float* taps_w = (const float*)d_in[4];
  const float* taps_b = (const float*)d_in[5];
  const float* w_out  = (const float*)d_in[6];
  const float* b_out  = (const float*)d_in[7];

  const int N = in_sizes[0] / 128;
  const int E = in_sizes[1] / 2;
  const int* src = ei;
  const int* dst = ei + E;
  const int NB = (N + (1 << BKT_SHIFT) - 1) >> BKT_SHIFT;

  // h (fp32) lives in d_out until the readout GEMM overwrites it.
  float* h = (float*)d_out;

  // workspace (~57 MB)
  const size_t yelem = (size_t)N * 128;
  ushort* y0 = (ushort*)d_ws;
  ushort* y1 = y0 + yelem;
  ushort* y2 = y1 + yelem;
  ushort* y3 = y2 + yelem;
  ushort* Wt_in  = y3 + yelem;             // 128*128
  ushort* Wt_out = Wt_in + 128 * 128;      // 128*128
  ushort* Wt_l0  = Wt_out + 128 * 128;     // 128*512
  ushort* Wt_l1  = Wt_l0 + 128 * 512;      // 128*512
  float*  bsum   = (float*)(Wt_l1 + 128 * 512);   // 256
  int*    rowp   = (int*)(bsum + 256);     // N+1
  int*    H      = rowp + (N + 1);         // NB*CSR_B
  uint*   packed = (uint*)(H + MAX_NB * CSR_B);   // E
  ushort* esrc   = (ushort*)(packed + E);  // E
  int*    cnts   = (int*)(esrc + E + (E & 1));    // 24 ints (4 per agg dispatch)

  const int gemmB = (N + 63) / 64;
  const int castB = (N * 16 + 255) / 256;
  const int aggB  = 2048;                  // persistent work-stealing blocks

  // ---- counters for agg work-stealing ----
  hipMemsetAsync(cnts, 0, 24 * sizeof(int), stream);

  // ---- CSR build (binned counting sort) ----
  chist_k<<<CSR_B, 256, 0, stream>>>(dst, H, E, NB);
  cscan_k<<<1, 256, 0, stream>>>(H, NB * CSR_B);
  cscatter_k<<<CSR_B, 256, 0, stream>>>(src, dst, H, packed, E, NB);
  fsort_k<<<NB, 256, 0, stream>>>(packed, H, esrc, rowp, N, E, NB);

  // ---- weight prep + x cast (chunked) ----
  prep_k<<<641, 256, 0, stream>>>(w_in, w_out, taps_w, taps_b,
                                  Wt_in, Wt_out, Wt_l0, Wt_l1, bsum);
  cast_f2b<<<castB, 256, 0, stream>>>(x, y1, N);

  // ---- readin: h = lrelu(x@Win+b); y0 = bf16(lrelu(h)) ----
  gemm_mfma<0, 128><<<gemmB, 256, 0, stream>>>(y1, y1, y1, y1, Wt_in, b_in, h, y0, 0, N);

  // ---- 2 residual graph-filter layers (cast fused into GEMM epilogue) ----
  int agg_i = 0;
  for (int l = 0; l < 2; l++) {
    const ushort* Wt_l = (l == 0) ? Wt_l0 : Wt_l1;
    agg_bf16<<<aggB, 256, 0, stream>>>(y0, y1, rowp, esrc, cnts + 4 * agg_i++, N);
    agg_bf16<<<aggB, 256, 0, stream>>>(y1, y2, rowp, esrc, cnts + 4 * agg_i++, N);
    agg_bf16<<<aggB, 256, 0, stream>>>(y2, y3, rowp, esrc, cnts + 4 * agg_i++, N);
    gemm_mfma<1, 512><<<gemmB, 256, 0, stream>>>(y0, y1, y2, y3, Wt_l, bsum + l * 128,
                                                 h, y0, (l == 0) ? 1 : 0, N);
  }

  // ---- readout: d_out = h @ Wout + bout (reads y0 = bf16(h)) ----
  gemm_mfma<2, 128><<<gemmB, 256, 0, stream>>>(y0, y0, y0, y0, Wt_out, b_out,
                                               (float*)d_out, nullptr, 0, N);
}

// Round 7
// 604.233 us; speedup vs baseline: 1.7676x; 1.7676x over previous
//
#include <hip/hip_runtime.h>

typedef unsigned int uint;
typedef unsigned short ushort;

using bf16x8 = __attribute__((ext_vector_type(8))) short;
using f32x4  = __attribute__((ext_vector_type(4))) float;

__device__ __forceinline__ float lrelu(float v) { return v > 0.f ? v : 0.01f * v; }
__device__ __forceinline__ float b2f(ushort u) { return __uint_as_float((uint)u << 16); }
__device__ __forceinline__ ushort f2b(float f) {
  uint u = __float_as_uint(f);
  u += 0x7fffu + ((u >> 16) & 1u);   // round-to-nearest-even
  return (ushort)(u >> 16);
}

// HW_REG_XCC_ID = hwreg id 20 (gfx940+); size 32, offset 0 -> encoding (31<<11)|20.
__device__ __forceinline__ uint get_xcc() {
  return (uint)__builtin_amdgcn_s_getreg((31 << 11) | 20) & 7u;
}

#define CSR_B 256          // blocks in coarse passes
#define BKT_SHIFT 10       // 1024 dst nodes per bucket
#define MAX_NB 64          // max buckets (N <= 65536)
#define AGG_BLOCKS 1024    // persistent agg blocks (4/CU)
#define ABATCH 8           // tiles per atomic grab
#define CNT_STRIDE 64      // ints between chunk counters (256 B -> separate lines)

// y buffers are CHANNEL-CHUNKED into 4 chunks of 32 ch: y[chunk][node][32].
// Row = 64 B = one cache line; chunk slab = N*64 B = 3.2 MB < 4 MiB per-XCD L2.
// agg pins chunk to XCD via HW_REG_XCC_ID (R6: FETCH 175->18 MB, confirmed) +
// batched, line-padded work-stealing counters (R6 post-mortem: unpadded
// single-line counters serialized ~11k RMWs ~= 140 us).

// ---------------------------------------------------------------------------
// MFMA GEMM: C[N,128] = A[N,K] @ W[K,128] + bias, bf16 in / fp32 acc.
// ---------------------------------------------------------------------------
template <int MODE, int K>
__global__ __launch_bounds__(256) void gemm_mfma(
    const ushort* __restrict__ A0, const ushort* __restrict__ A1,
    const ushort* __restrict__ A2, const ushort* __restrict__ A3,
    const ushort* __restrict__ Wt, const float* __restrict__ bias,
    float* __restrict__ h, ushort* __restrict__ yout, int do_act, int N) {
  __shared__ ushort As[64][40];    // [m][k], stride 40 (16B-aligned, 2-way-free banks)
  __shared__ ushort Bs[128][40];   // [n][k]
  const int tid = threadIdx.x;
  const int lane = tid & 63;
  const int wave = tid >> 6;
  const int g = lane >> 4;         // k-quad
  const int mr = lane & 15;
  const int wr = wave >> 1;        // row half
  const int wc = wave & 1;         // col half
  const int row0 = blockIdx.x * 64;

  const ushort* Ap[4] = {A0, A1, A2, A3};

  f32x4 acc[2][4];
#pragma unroll
  for (int i = 0; i < 2; i++)
#pragma unroll
    for (int j = 0; j < 4; j++) acc[i][j] = (f32x4){0.f, 0.f, 0.f, 0.f};

#pragma unroll 4
  for (int kc = 0; kc < K; kc += 32) {
    {  // stage A: 64 rows x 32 k (one uint4 per thread), 4x32-chunked layout
      int m = tid >> 2, q = tid & 3;
      int r = row0 + m;
      if (r >= N) r = N - 1;
      int kg = kc + q * 8;
      const ushort* ap = Ap[kg >> 7] + ((size_t)((kg >> 5) & 3)) * N * 32 +
                         (size_t)r * 32 + (kg & 31);
      *(uint4*)&As[m][q * 8] = *(const uint4*)ap;
    }
#pragma unroll
    for (int t = 0; t < 2; t++) {  // stage B: 128 n x 32 k
      int slot = tid + t * 256;
      int n = slot >> 2, q = slot & 3;
      *(uint4*)&Bs[n][q * 8] = *(const uint4*)(Wt + (size_t)n * K + kc + q * 8);
    }
    __syncthreads();
    bf16x8 af[2], bf[4];
#pragma unroll
    for (int rt = 0; rt < 2; rt++) af[rt] = *(bf16x8*)&As[wr * 32 + rt * 16 + mr][g * 8];
#pragma unroll
    for (int ct = 0; ct < 4; ct++) bf[ct] = *(bf16x8*)&Bs[wc * 64 + ct * 16 + mr][g * 8];
#pragma unroll
    for (int rt = 0; rt < 2; rt++)
#pragma unroll
      for (int ct = 0; ct < 4; ct++)
        acc[rt][ct] = __builtin_amdgcn_mfma_f32_16x16x32_bf16(af[rt], bf[ct], acc[rt][ct], 0, 0, 0);
    __syncthreads();
  }

  // epilogue: C/D layout col=lane&15, row=(lane>>4)*4+reg
#pragma unroll
  for (int rt = 0; rt < 2; rt++) {
#pragma unroll
    for (int i = 0; i < 4; i++) {
      int R = row0 + wr * 32 + rt * 16 + g * 4 + i;
      if (R >= N) continue;
#pragma unroll
      for (int ct = 0; ct < 4; ct++) {
        int c = wc * 64 + ct * 16 + mr;       // chunk = c>>5, within = c&31
        float v = acc[rt][ct][i] + bias[c];
        size_t o = (size_t)R * 128 + c;
        size_t oy = (size_t)(c >> 5) * N * 32 + (size_t)R * 32 + (c & 31);
        if (MODE == 0) {
          float hv = lrelu(v);
          h[o] = hv;
          yout[oy] = f2b(lrelu(hv));
        } else if (MODE == 1) {
          float hv = h[o] + v;
          h[o] = hv;
          if (yout) yout[oy] = f2b(do_act ? lrelu(hv) : hv);
        } else {
          h[o] = v;
        }
      }
    }
  }
}

// ---------------- bf16 aggregation, XCD-pinned persistent kernel -------------
// chunk = XCC_ID&3; batches of ABATCH 64-node tiles per atomic grab from
// line-padded per-chunk counters; falls over to other chunks when exhausted.
// 4 lanes x uint4 (16 B) per node = one 64 B line per edge-gather; 8-deep unroll.
__global__ __launch_bounds__(256) void agg_bf16(const ushort* __restrict__ yin,
                                                ushort* __restrict__ yout,
                                                const int* __restrict__ rowp,
                                                const ushort* __restrict__ esrc,
                                                int* __restrict__ cnt, int N) {
  __shared__ int s_tile;
  const int T = (N + 63) >> 6;   // tiles per chunk
  const int t = threadIdx.x;
  const int lane = t & 3;
  const int nsub = t >> 2;
  const uint mychunk = get_xcc() & 3u;

  for (int c = 0; c < 4; c++) {
    const int chunk = (int)((mychunk + c) & 3u);
    const ushort* yb = yin + (size_t)chunk * N * 32 + lane * 8;
    ushort* yo = yout + (size_t)chunk * N * 32 + lane * 8;
    while (true) {
      if (t == 0) s_tile = atomicAdd(&cnt[chunk * CNT_STRIDE], ABATCH);
      __syncthreads();
      const int tile0 = s_tile;
      __syncthreads();
      if (tile0 >= T) break;
      const int tend = min(T, tile0 + ABATCH);
      for (int tile = tile0; tile < tend; tile++) {
        const int node = tile * 64 + nsub;
        if (node >= N) continue;
        const int beg = rowp[node], end = rowp[node + 1];
        float s[8] = {0.f, 0.f, 0.f, 0.f, 0.f, 0.f, 0.f, 0.f};
        int j = beg;
        for (; j + 8 <= end; j += 8) {
          union { uint4 v; ushort u[8]; } w[8];
#pragma unroll
          for (int u = 0; u < 8; u++) {
            int sn = esrc[j + u];
            w[u].v = *(const uint4*)(yb + (size_t)sn * 32);
          }
#pragma unroll
          for (int e = 0; e < 8; e++) {
            float a = 0.f;
#pragma unroll
            for (int u = 0; u < 8; u++) a += b2f(w[u].u[e]);
            s[e] += a;
          }
        }
        for (; j < end; j++) {
          int sn = esrc[j];
          union { uint4 v; ushort u[8]; } w;
          w.v = *(const uint4*)(yb + (size_t)sn * 32);
#pragma unroll
          for (int e = 0; e < 8; e++) s[e] += b2f(w.u[e]);
        }
        union { uint4 v; ushort u[8]; } o;
#pragma unroll
        for (int e = 0; e < 8; e++) o.u[e] = f2b(s[e]);
        *(uint4*)(yo + (size_t)node * 32) = o.v;
      }
    }
  }
}

// ---------------- fp32 [N][128] -> bf16 chunked y ----------------
__global__ __launch_bounds__(256) void cast_f2b(const float* __restrict__ in,
                                                ushort* __restrict__ out, int N) {
  int i = blockIdx.x * 256 + threadIdx.x;
  if (i >= N * 16) return;
  int node = i >> 4, sub = i & 15;           // 8 channels per thread
  float4 a = *(const float4*)(in + (size_t)node * 128 + sub * 8);
  float4 b = *(const float4*)(in + (size_t)node * 128 + sub * 8 + 4);
  float v[8] = {a.x, a.y, a.z, a.w, b.x, b.y, b.z, b.w};
  union { uint4 q; ushort u[8]; } o;
#pragma unroll
  for (int e = 0; e < 8; e++) o.u[e] = f2b(v[e]);
  int chunk = sub >> 2, off = (sub & 3) * 8;
  *(uint4*)(out + (size_t)chunk * N * 32 + (size_t)node * 32 + off) = o.q;
}

// ---------------- weight prep: cast + transpose + bias sums ------------------
__global__ __launch_bounds__(256) void prep_k(const float* __restrict__ w_in,
                                              const float* __restrict__ w_out,
                                              const float* __restrict__ taps_w,
                                              const float* __restrict__ taps_b,
                                              ushort* __restrict__ Wt_in,
                                              ushort* __restrict__ Wt_out,
                                              ushort* __restrict__ Wt_l0,
                                              ushort* __restrict__ Wt_l1,
                                              float* __restrict__ bsum) {
  int gid = blockIdx.x * 256 + threadIdx.x;
  if (gid < 16384) {
    int n = gid >> 7, k = gid & 127;
    Wt_in[gid] = f2b(w_in[k * 128 + n]);
  } else if (gid < 32768) {
    int i = gid - 16384;
    int n = i >> 7, k = i & 127;
    Wt_out[i] = f2b(w_out[k * 128 + n]);
  } else if (gid < 98304) {
    int i = gid - 32768;
    int n = i >> 9, k = i & 511;
    Wt_l0[i] = f2b(taps_w[(size_t)k * 128 + n]);
  } else if (gid < 163840) {
    int i = gid - 98304;
    int n = i >> 9, k = i & 511;
    Wt_l1[i] = f2b(taps_w[(size_t)(512 + k) * 128 + n]);
  } else if (gid < 164096) {
    int i = gid - 163840;
    int l = i >> 7, n = i & 127;
    float s = 0.f;
    for (int k = 0; k < 4; k++) s += taps_b[l * 512 + k * 128 + n];
    bsum[i] = s;
  }
}

// ---------------- CSR build: 2-level binned counting sort --------------------
__global__ __launch_bounds__(256) void chist_k(const int* __restrict__ dst,
                                               int* __restrict__ H, int E, int NB) {
  __shared__ int hh[MAX_NB];
  if (threadIdx.x < NB) hh[threadIdx.x] = 0;
  __syncthreads();
  int chunk = (E + gridDim.x - 1) / gridDim.x;
  int beg = blockIdx.x * chunk, end = min(E, beg + chunk);
  for (int e = beg + threadIdx.x; e < end; e += 256)
    atomicAdd(&hh[dst[e] >> BKT_SHIFT], 1);
  __syncthreads();
  if (threadIdx.x < NB) H[threadIdx.x * gridDim.x + blockIdx.x] = hh[threadIdx.x];
}

__global__ __launch_bounds__(256) void cscan_k(int* __restrict__ H, int M) {
  __shared__ int sm[256];
  int per = (M + 255) / 256;
  int b0 = threadIdx.x * per;
  int hi = min(M, b0 + per);
  int sum = 0;
  for (int i = b0; i < hi; i++) sum += H[i];
  sm[threadIdx.x] = sum;
  __syncthreads();
  int x = sum;
  for (int off = 1; off < 256; off <<= 1) {
    int tt = (threadIdx.x >= off) ? sm[threadIdx.x - off] : 0;
    __syncthreads();
    x += tt;
    sm[threadIdx.x] = x;
    __syncthreads();
  }
  int run = x - sum;  // exclusive
  for (int i = b0; i < hi; i++) {
    int v = H[i];
    H[i] = run;
    run += v;
  }
}

__global__ __launch_bounds__(256) void cscatter_k(const int* __restrict__ src,
                                                  const int* __restrict__ dst,
                                                  const int* __restrict__ H,
                                                  uint* __restrict__ packed,
                                                  int E, int NB) {
  __shared__ int cur[MAX_NB];
  int chunk = (E + gridDim.x - 1) / gridDim.x;
  int beg = blockIdx.x * chunk, end = min(E, beg + chunk);
  if (threadIdx.x < NB) cur[threadIdx.x] = H[threadIdx.x * gridDim.x + blockIdx.x];
  __syncthreads();
  for (int e = beg + threadIdx.x; e < end; e += 256) {
    int d = dst[e];
    int pos = atomicAdd(&cur[d >> BKT_SHIFT], 1);
    packed[pos] = ((uint)d << 16) | (uint)src[e];
  }
}

__global__ __launch_bounds__(256) void fsort_k(const uint* __restrict__ packed,
                                               const int* __restrict__ H,
                                               ushort* __restrict__ esrc,
                                               int* __restrict__ rowp,
                                               int N, int E, int NB) {
  __shared__ int hist[1 << BKT_SHIFT];
  __shared__ int cur[1 << BKT_SHIFT];
  __shared__ int sm[256];
  const int bkt = blockIdx.x;
  const int base = bkt << BKT_SHIFT;
  const int nb_nodes = min(1 << BKT_SHIFT, N - base);
  const int start = H[bkt * CSR_B];
  const int end = (bkt == NB - 1) ? E : H[(bkt + 1) * CSR_B];

  for (int i = threadIdx.x; i < (1 << BKT_SHIFT); i += 256) hist[i] = 0;
  __syncthreads();
  for (int e = start + threadIdx.x; e < end; e += 256)
    atomicAdd(&hist[(packed[e] >> 16) - base], 1);
  __syncthreads();

  int t4 = threadIdx.x * 4;
  int l0 = hist[t4], l1 = hist[t4 + 1], l2 = hist[t4 + 2], l3 = hist[t4 + 3];
  int ssum = l0 + l1 + l2 + l3;
  sm[threadIdx.x] = ssum;
  __syncthreads();
  int x = ssum;
  for (int off = 1; off < 256; off <<= 1) {
    int tt = (threadIdx.x >= off) ? sm[threadIdx.x - off] : 0;
    __syncthreads();
    x += tt;
    sm[threadIdx.x] = x;
    __syncthreads();
  }
  int c0 = start + x - ssum;
  int c1 = c0 + l0, c2 = c1 + l1, c3 = c2 + l2;
  cur[t4] = c0; cur[t4 + 1] = c1; cur[t4 + 2] = c2; cur[t4 + 3] = c3;
  if (t4 + 0 < nb_nodes) rowp[base + t4 + 0] = c0;
  if (t4 + 1 < nb_nodes) rowp[base + t4 + 1] = c1;
  if (t4 + 2 < nb_nodes) rowp[base + t4 + 2] = c2;
  if (t4 + 3 < nb_nodes) rowp[base + t4 + 3] = c3;
  __syncthreads();

  for (int e = start + threadIdx.x; e < end; e += 256) {
    uint p = packed[e];
    int pos = atomicAdd(&cur[(p >> 16) - base], 1);
    esrc[pos] = (ushort)(p & 0xffffu);
  }
  if (bkt == 0 && threadIdx.x == 0) rowp[N] = E;
}

// ---------------------------------------------------------------------------
extern "C" void kernel_launch(void* const* d_in, const int* in_sizes, int n_in,
                              void* d_out, int out_size, void* d_ws, size_t ws_size,
                              hipStream_t stream) {
  const float* x      = (const float*)d_in[0];
  const int*   ei     = (const int*)d_in[1];
  const float* w_in   = (const float*)d_in[2];
  const float* b_in   = (const float*)d_in[3];
  const float* taps_w = (const float*)d_in[4];
  const float* taps_b = (const float*)d_in[5];
  const float* w_out  = (const float*)d_in[6];
  const float* b_out  = (const float*)d_in[7];

  const int N = in_sizes[0] / 128;
  const int E = in_sizes[1] / 2;
  const int* src = ei;
  const int* dst = ei + E;
  const int NB = (N + (1 << BKT_SHIFT) - 1) >> BKT_SHIFT;

  // h (fp32) lives in d_out until the readout GEMM overwrites it.
  float* h = (float*)d_out;

  // workspace (~57 MB)
  const size_t yelem = (size_t)N * 128;
  ushort* y0 = (ushort*)d_ws;
  ushort* y1 = y0 + yelem;
  ushort* y2 = y1 + yelem;
  ushort* y3 = y2 + yelem;
  ushort* Wt_in  = y3 + yelem;             // 128*128
  ushort* Wt_out = Wt_in + 128 * 128;      // 128*128
  ushort* Wt_l0  = Wt_out + 128 * 128;     // 128*512
  ushort* Wt_l1  = Wt_l0 + 128 * 512;      // 128*512
  float*  bsum   = (float*)(Wt_l1 + 128 * 512);   // 256
  int*    rowp   = (int*)(bsum + 256);     // N+1
  int*    H      = rowp + (N + 1);         // NB*CSR_B
  uint*   packed = (uint*)(H + MAX_NB * CSR_B);   // E
  ushort* esrc   = (ushort*)(packed + E);  // E
  int*    cnts   = (int*)(esrc + E + (E & 1));    // 6 dispatches x 4 x CNT_STRIDE

  const int gemmB = (N + 63) / 64;
  const int castB = (N * 16 + 255) / 256;

  // ---- counters for agg work-stealing (line-padded) ----
  hipMemsetAsync(cnts, 0, 6 * 4 * CNT_STRIDE * sizeof(int), stream);

  // ---- CSR build (binned counting sort) ----
  chist_k<<<CSR_B, 256, 0, stream>>>(dst, H, E, NB);
  cscan_k<<<1, 256, 0, stream>>>(H, NB * CSR_B);
  cscatter_k<<<CSR_B, 256, 0, stream>>>(src, dst, H, packed, E, NB);
  fsort_k<<<NB, 256, 0, stream>>>(packed, H, esrc, rowp, N, E, NB);

  // ---- weight prep + x cast (chunked) ----
  prep_k<<<641, 256, 0, stream>>>(w_in, w_out, taps_w, taps_b,
                                  Wt_in, Wt_out, Wt_l0, Wt_l1, bsum);
  cast_f2b<<<castB, 256, 0, stream>>>(x, y1, N);

  // ---- readin: h = lrelu(x@Win+b); y0 = bf16(lrelu(h)) ----
  gemm_mfma<0, 128><<<gemmB, 256, 0, stream>>>(y1, y1, y1, y1, Wt_in, b_in, h, y0, 0, N);

  // ---- 2 residual graph-filter layers (cast fused into GEMM epilogue) ----
  int agg_i = 0;
  for (int l = 0; l < 2; l++) {
    const ushort* Wt_l = (l == 0) ? Wt_l0 : Wt_l1;
    agg_bf16<<<AGG_BLOCKS, 256, 0, stream>>>(y0, y1, rowp, esrc,
                                             cnts + 4 * CNT_STRIDE * agg_i++, N);
    agg_bf16<<<AGG_BLOCKS, 256, 0, stream>>>(y1, y2, rowp, esrc,
                                             cnts + 4 * CNT_STRIDE * agg_i++, N);
    agg_bf16<<<AGG_BLOCKS, 256, 0, stream>>>(y2, y3, rowp, esrc,
                                             cnts + 4 * CNT_STRIDE * agg_i++, N);
    gemm_mfma<1, 512><<<gemmB, 256, 0, stream>>>(y0, y1, y2, y3, Wt_l, bsum + l * 128,
                                                 h, y0, (l == 0) ? 1 : 0, N);
  }

  // ---- readout: d_out = h @ Wout + bout (reads y0 = bf16(h)) ----
  gemm_mfma<2, 128><<<gemmB, 256, 0, stream>>>(y0, y0, y0, y0, Wt_out, b_out,
                                               (float*)d_out, nullptr, 0, N);
}

// Round 8
// 503.567 us; speedup vs baseline: 2.1210x; 1.1999x over previous
//
#include <hip/hip_runtime.h>

typedef unsigned int uint;
typedef unsigned short ushort;

using bf16x8 = __attribute__((ext_vector_type(8))) short;
using f32x4  = __attribute__((ext_vector_type(4))) float;

__device__ __forceinline__ float lrelu(float v) { return v > 0.f ? v : 0.01f * v; }
__device__ __forceinline__ float b2f(ushort u) { return __uint_as_float((uint)u << 16); }
__device__ __forceinline__ ushort f2b(float f) {
  uint u = __float_as_uint(f);
  u += 0x7fffu + ((u >> 16) & 1u);   // round-to-nearest-even
  return (ushort)(u >> 16);
}

// HW_REG_XCC_ID = hwreg id 20 (gfx940+); size 32, offset 0 -> encoding (31<<11)|20.
__device__ __forceinline__ uint get_xcc() {
  return (uint)__builtin_amdgcn_s_getreg((31 << 11) | 20) & 7u;
}

#define CSR_B 256          // blocks in coarse passes
#define BKT_SHIFT 10       // 1024 dst nodes per bucket
#define MAX_NB 64          // max buckets (N <= 65536)
#define AGG_BLOCKS 1024    // persistent agg blocks (4/CU)
#define ABATCH 3           // tiles per atomic grab (~261 batches/chunk ~ blocks/chunk)
#define CNT_STRIDE 64      // ints between counters (256 B -> separate lines)

// y buffers are CHANNEL-CHUNKED into 4 chunks of 32 ch: y[chunk][node][32].
// Row = 64 B = one cache line; chunk slab = N*64 B = 3.2 MB < 4 MiB per-XCD L2.
// agg pins chunk to XCD via HW_REG_XCC_ID (R6: FETCH 175->18 MB, confirmed).
// R7 lesson: probes-as-RMW serialized (~13 ns/op global) -> probes are now
// relaxed LOADS; 8 line-padded counters (chunk x XCD-half) cut per-line RMWs.

// ---------------------------------------------------------------------------
// MFMA GEMM: C[N,128] = A[N,K] @ W[K,128] + bias, bf16 in / fp32 acc.
// ---------------------------------------------------------------------------
template <int MODE, int K>
__global__ __launch_bounds__(256) void gemm_mfma(
    const ushort* __restrict__ A0, const ushort* __restrict__ A1,
    const ushort* __restrict__ A2, const ushort* __restrict__ A3,
    const ushort* __restrict__ Wt, const float* __restrict__ bias,
    float* __restrict__ h, ushort* __restrict__ yout, int do_act, int N) {
  __shared__ ushort As[64][40];    // [m][k], stride 40 (16B-aligned, 2-way-free banks)
  __shared__ ushort Bs[128][40];   // [n][k]
  const int tid = threadIdx.x;
  const int lane = tid & 63;
  const int wave = tid >> 6;
  const int g = lane >> 4;         // k-quad
  const int mr = lane & 15;
  const int wr = wave >> 1;        // row half
  const int wc = wave & 1;         // col half
  const int row0 = blockIdx.x * 64;

  const ushort* Ap[4] = {A0, A1, A2, A3};

  f32x4 acc[2][4];
#pragma unroll
  for (int i = 0; i < 2; i++)
#pragma unroll
    for (int j = 0; j < 4; j++) acc[i][j] = (f32x4){0.f, 0.f, 0.f, 0.f};

#pragma unroll 4
  for (int kc = 0; kc < K; kc += 32) {
    {  // stage A: 64 rows x 32 k (one uint4 per thread), 4x32-chunked layout
      int m = tid >> 2, q = tid & 3;
      int r = row0 + m;
      if (r >= N) r = N - 1;
      int kg = kc + q * 8;
      const ushort* ap = Ap[kg >> 7] + ((size_t)((kg >> 5) & 3)) * N * 32 +
                         (size_t)r * 32 + (kg & 31);
      *(uint4*)&As[m][q * 8] = *(const uint4*)ap;
    }
#pragma unroll
    for (int t = 0; t < 2; t++) {  // stage B: 128 n x 32 k
      int slot = tid + t * 256;
      int n = slot >> 2, q = slot & 3;
      *(uint4*)&Bs[n][q * 8] = *(const uint4*)(Wt + (size_t)n * K + kc + q * 8);
    }
    __syncthreads();
    bf16x8 af[2], bf[4];
#pragma unroll
    for (int rt = 0; rt < 2; rt++) af[rt] = *(bf16x8*)&As[wr * 32 + rt * 16 + mr][g * 8];
#pragma unroll
    for (int ct = 0; ct < 4; ct++) bf[ct] = *(bf16x8*)&Bs[wc * 64 + ct * 16 + mr][g * 8];
#pragma unroll
    for (int rt = 0; rt < 2; rt++)
#pragma unroll
      for (int ct = 0; ct < 4; ct++)
        acc[rt][ct] = __builtin_amdgcn_mfma_f32_16x16x32_bf16(af[rt], bf[ct], acc[rt][ct], 0, 0, 0);
    __syncthreads();
  }

  // epilogue: C/D layout col=lane&15, row=(lane>>4)*4+reg
#pragma unroll
  for (int rt = 0; rt < 2; rt++) {
#pragma unroll
    for (int i = 0; i < 4; i++) {
      int R = row0 + wr * 32 + rt * 16 + g * 4 + i;
      if (R >= N) continue;
#pragma unroll
      for (int ct = 0; ct < 4; ct++) {
        int c = wc * 64 + ct * 16 + mr;       // chunk = c>>5, within = c&31
        float v = acc[rt][ct][i] + bias[c];
        size_t o = (size_t)R * 128 + c;
        size_t oy = (size_t)(c >> 5) * N * 32 + (size_t)R * 32 + (c & 31);
        if (MODE == 0) {
          float hv = lrelu(v);
          h[o] = hv;
          yout[oy] = f2b(lrelu(hv));
        } else if (MODE == 1) {
          float hv = h[o] + v;
          h[o] = hv;
          if (yout) yout[oy] = f2b(do_act ? lrelu(hv) : hv);
        } else {
          h[o] = v;
        }
      }
    }
  }
}

// ---------------- bf16 aggregation, XCD-pinned persistent kernel -------------
// 8 work queues: (chunk, tile-half). Block starts on (xcc&3, xcc>>2), then the
// other half of its chunk, then other chunks. Exhaustion probes are relaxed
// atomic LOADS (no exclusive line transfer); only sub-limit values trigger the
// real atomicAdd. Coverage: every tile index < limit is returned exactly once.
__global__ __launch_bounds__(256) void agg_bf16(const ushort* __restrict__ yin,
                                                ushort* __restrict__ yout,
                                                const int* __restrict__ rowp,
                                                const ushort* __restrict__ esrc,
                                                int* __restrict__ cnt, int N) {
  __shared__ int s_tile;
  const int T = (N + 63) >> 6;    // tiles per chunk
  const int Th = (T + 1) >> 1;    // tiles per half
  const int t = threadIdx.x;
  const int lane = t & 3;
  const int nsub = t >> 2;
  const uint xcc = get_xcc();
  const uint mychunk = xcc & 3u;
  const uint myhalf = (xcc >> 2) & 1u;

  for (int cc = 0; cc < 8; cc++) {
    const int chunk = (int)((mychunk + (uint)(cc >> 1)) & 3u);
    const int half = (int)(myhalf ^ (uint)(cc & 1));
    const int tbeg = half * Th;
    const int tcnt = min(T - tbeg, Th);
    if (tcnt <= 0) continue;
    int* ctr = &cnt[(chunk * 2 + half) * CNT_STRIDE];
    const ushort* yb = yin + (size_t)chunk * N * 32 + lane * 8;
    ushort* yo = yout + (size_t)chunk * N * 32 + lane * 8;
    while (true) {
      if (t == 0) {
        int seen = __hip_atomic_load(ctr, __ATOMIC_RELAXED, __HIP_MEMORY_SCOPE_AGENT);
        s_tile = (seen >= tcnt) ? tcnt : atomicAdd(ctr, ABATCH);
      }
      __syncthreads();
      const int rel0 = s_tile;
      __syncthreads();
      if (rel0 >= tcnt) break;
      const int rend = min(tcnt, rel0 + ABATCH);
      for (int rt = rel0; rt < rend; rt++) {
        const int node = (tbeg + rt) * 64 + nsub;
        if (node >= N) continue;
        const int beg = rowp[node], end = rowp[node + 1];
        float s[8] = {0.f, 0.f, 0.f, 0.f, 0.f, 0.f, 0.f, 0.f};
        int j = beg;
        for (; j + 8 <= end; j += 8) {
          union { uint4 v; ushort u[8]; } w[8];
#pragma unroll
          for (int u = 0; u < 8; u++) {
            int sn = esrc[j + u];
            w[u].v = *(const uint4*)(yb + (size_t)sn * 32);
          }
#pragma unroll
          for (int e = 0; e < 8; e++) {
            float a = 0.f;
#pragma unroll
            for (int u = 0; u < 8; u++) a += b2f(w[u].u[e]);
            s[e] += a;
          }
        }
        for (; j < end; j++) {
          int sn = esrc[j];
          union { uint4 v; ushort u[8]; } w;
          w.v = *(const uint4*)(yb + (size_t)sn * 32);
#pragma unroll
          for (int e = 0; e < 8; e++) s[e] += b2f(w.u[e]);
        }
        union { uint4 v; ushort u[8]; } o;
#pragma unroll
        for (int e = 0; e < 8; e++) o.u[e] = f2b(s[e]);
        *(uint4*)(yo + (size_t)node * 32) = o.v;
      }
    }
  }
}

// ---------------- fp32 [N][128] -> bf16 chunked y ----------------
__global__ __launch_bounds__(256) void cast_f2b(const float* __restrict__ in,
                                                ushort* __restrict__ out, int N) {
  int i = blockIdx.x * 256 + threadIdx.x;
  if (i >= N * 16) return;
  int node = i >> 4, sub = i & 15;           // 8 channels per thread
  float4 a = *(const float4*)(in + (size_t)node * 128 + sub * 8);
  float4 b = *(const float4*)(in + (size_t)node * 128 + sub * 8 + 4);
  float v[8] = {a.x, a.y, a.z, a.w, b.x, b.y, b.z, b.w};
  union { uint4 q; ushort u[8]; } o;
#pragma unroll
  for (int e = 0; e < 8; e++) o.u[e] = f2b(v[e]);
  int chunk = sub >> 2, off = (sub & 3) * 8;
  *(uint4*)(out + (size_t)chunk * N * 32 + (size_t)node * 32 + off) = o.q;
}

// ---------------- weight prep: cast + transpose + bias sums ------------------
__global__ __launch_bounds__(256) void prep_k(const float* __restrict__ w_in,
                                              const float* __restrict__ w_out,
                                              const float* __restrict__ taps_w,
                                              const float* __restrict__ taps_b,
                                              ushort* __restrict__ Wt_in,
                                              ushort* __restrict__ Wt_out,
                                              ushort* __restrict__ Wt_l0,
                                              ushort* __restrict__ Wt_l1,
                                              float* __restrict__ bsum) {
  int gid = blockIdx.x * 256 + threadIdx.x;
  if (gid < 16384) {
    int n = gid >> 7, k = gid & 127;
    Wt_in[gid] = f2b(w_in[k * 128 + n]);
  } else if (gid < 32768) {
    int i = gid - 16384;
    int n = i >> 7, k = i & 127;
    Wt_out[i] = f2b(w_out[k * 128 + n]);
  } else if (gid < 98304) {
    int i = gid - 32768;
    int n = i >> 9, k = i & 511;
    Wt_l0[i] = f2b(taps_w[(size_t)k * 128 + n]);
  } else if (gid < 163840) {
    int i = gid - 98304;
    int n = i >> 9, k = i & 511;
    Wt_l1[i] = f2b(taps_w[(size_t)(512 + k) * 128 + n]);
  } else if (gid < 164096) {
    int i = gid - 163840;
    int l = i >> 7, n = i & 127;
    float s = 0.f;
    for (int k = 0; k < 4; k++) s += taps_b[l * 512 + k * 128 + n];
    bsum[i] = s;
  }
}

// ---------------- CSR build: 2-level binned counting sort --------------------
__global__ __launch_bounds__(256) void chist_k(const int* __restrict__ dst,
                                               int* __restrict__ H, int E, int NB) {
  __shared__ int hh[MAX_NB];
  if (threadIdx.x < NB) hh[threadIdx.x] = 0;
  __syncthreads();
  int chunk = (E + gridDim.x - 1) / gridDim.x;
  int beg = blockIdx.x * chunk, end = min(E, beg + chunk);
  for (int e = beg + threadIdx.x; e < end; e += 256)
    atomicAdd(&hh[dst[e] >> BKT_SHIFT], 1);
  __syncthreads();
  if (threadIdx.x < NB) H[threadIdx.x * gridDim.x + blockIdx.x] = hh[threadIdx.x];
}

__global__ __launch_bounds__(256) void cscan_k(int* __restrict__ H, int M) {
  __shared__ int sm[256];
  int per = (M + 255) / 256;
  int b0 = threadIdx.x * per;
  int hi = min(M, b0 + per);
  int sum = 0;
  for (int i = b0; i < hi; i++) sum += H[i];
  sm[threadIdx.x] = sum;
  __syncthreads();
  int x = sum;
  for (int off = 1; off < 256; off <<= 1) {
    int tt = (threadIdx.x >= off) ? sm[threadIdx.x - off] : 0;
    __syncthreads();
    x += tt;
    sm[threadIdx.x] = x;
    __syncthreads();
  }
  int run = x - sum;  // exclusive
  for (int i = b0; i < hi; i++) {
    int v = H[i];
    H[i] = run;
    run += v;
  }
}

__global__ __launch_bounds__(256) void cscatter_k(const int* __restrict__ src,
                                                  const int* __restrict__ dst,
                                                  const int* __restrict__ H,
                                                  uint* __restrict__ packed,
                                                  int E, int NB) {
  __shared__ int cur[MAX_NB];
  int chunk = (E + gridDim.x - 1) / gridDim.x;
  int beg = blockIdx.x * chunk, end = min(E, beg + chunk);
  if (threadIdx.x < NB) cur[threadIdx.x] = H[threadIdx.x * gridDim.x + blockIdx.x];
  __syncthreads();
  for (int e = beg + threadIdx.x; e < end; e += 256) {
    int d = dst[e];
    int pos = atomicAdd(&cur[d >> BKT_SHIFT], 1);
    packed[pos] = ((uint)d << 16) | (uint)src[e];
  }
}

__global__ __launch_bounds__(256) void fsort_k(const uint* __restrict__ packed,
                                               const int* __restrict__ H,
                                               ushort* __restrict__ esrc,
                                               int* __restrict__ rowp,
                                               int N, int E, int NB) {
  __shared__ int hist[1 << BKT_SHIFT];
  __shared__ int cur[1 << BKT_SHIFT];
  __shared__ int sm[256];
  const int bkt = blockIdx.x;
  const int base = bkt << BKT_SHIFT;
  const int nb_nodes = min(1 << BKT_SHIFT, N - base);
  const int start = H[bkt * CSR_B];
  const int end = (bkt == NB - 1) ? E : H[(bkt + 1) * CSR_B];

  for (int i = threadIdx.x; i < (1 << BKT_SHIFT); i += 256) hist[i] = 0;
  __syncthreads();
  for (int e = start + threadIdx.x; e < end; e += 256)
    atomicAdd(&hist[(packed[e] >> 16) - base], 1);
  __syncthreads();

  int t4 = threadIdx.x * 4;
  int l0 = hist[t4], l1 = hist[t4 + 1], l2 = hist[t4 + 2], l3 = hist[t4 + 3];
  int ssum = l0 + l1 + l2 + l3;
  sm[threadIdx.x] = ssum;
  __syncthreads();
  int x = ssum;
  for (int off = 1; off < 256; off <<= 1) {
    int tt = (threadIdx.x >= off) ? sm[threadIdx.x - off] : 0;
    __syncthreads();
    x += tt;
    sm[threadIdx.x] = x;
    __syncthreads();
  }
  int c0 = start + x - ssum;
  int c1 = c0 + l0, c2 = c1 + l1, c3 = c2 + l2;
  cur[t4] = c0; cur[t4 + 1] = c1; cur[t4 + 2] = c2; cur[t4 + 3] = c3;
  if (t4 + 0 < nb_nodes) rowp[base + t4 + 0] = c0;
  if (t4 + 1 < nb_nodes) rowp[base + t4 + 1] = c1;
  if (t4 + 2 < nb_nodes) rowp[base + t4 + 2] = c2;
  if (t4 + 3 < nb_nodes) rowp[base + t4 + 3] = c3;
  __syncthreads();

  for (int e = start + threadIdx.x; e < end; e += 256) {
    uint p = packed[e];
    int pos = atomicAdd(&cur[(p >> 16) - base], 1);
    esrc[pos] = (ushort)(p & 0xffffu);
  }
  if (bkt == 0 && threadIdx.x == 0) rowp[N] = E;
}

// ---------------------------------------------------------------------------
extern "C" void kernel_launch(void* const* d_in, const int* in_sizes, int n_in,
                              void* d_out, int out_size, void* d_ws, size_t ws_size,
                              hipStream_t stream) {
  const float* x      = (const float*)d_in[0];
  const int*   ei     = (const int*)d_in[1];
  const float* w_in   = (const float*)d_in[2];
  const float* b_in   = (const float*)d_in[3];
  const float* taps_w = (const float*)d_in[4];
  const float* taps_b = (const float*)d_in[5];
  const float* w_out  = (const float*)d_in[6];
  const float* b_out  = (const float*)d_in[7];

  const int N = in_sizes[0] / 128;
  const int E = in_sizes[1] / 2;
  const int* src = ei;
  const int* dst = ei + E;
  const int NB = (N + (1 << BKT_SHIFT) - 1) >> BKT_SHIFT;

  // h (fp32) lives in d_out until the readout GEMM overwrites it.
  float* h = (float*)d_out;

  // workspace (~57 MB)
  const size_t yelem = (size_t)N * 128;
  ushort* y0 = (ushort*)d_ws;
  ushort* y1 = y0 + yelem;
  ushort* y2 = y1 + yelem;
  ushort* y3 = y2 + yelem;
  ushort* Wt_in  = y3 + yelem;             // 128*128
  ushort* Wt_out = Wt_in + 128 * 128;      // 128*128
  ushort* Wt_l0  = Wt_out + 128 * 128;     // 128*512
  ushort* Wt_l1  = Wt_l0 + 128 * 512;      // 128*512
  float*  bsum   = (float*)(Wt_l1 + 128 * 512);   // 256
  int*    rowp   = (int*)(bsum + 256);     // N+1
  int*    H      = rowp + (N + 1);         // NB*CSR_B
  uint*   packed = (uint*)(H + MAX_NB * CSR_B);   // E
  ushort* esrc   = (ushort*)(packed + E);  // E
  int*    cnts   = (int*)(esrc + E + (E & 1));    // 6 dispatches x 8 x CNT_STRIDE

  const int gemmB = (N + 63) / 64;
  const int castB = (N * 16 + 255) / 256;

  // ---- counters for agg work-stealing (8 line-padded queues per dispatch) ----
  hipMemsetAsync(cnts, 0, 6 * 8 * CNT_STRIDE * sizeof(int), stream);

  // ---- CSR build (binned counting sort) ----
  chist_k<<<CSR_B, 256, 0, stream>>>(dst, H, E, NB);
  cscan_k<<<1, 256, 0, stream>>>(H, NB * CSR_B);
  cscatter_k<<<CSR_B, 256, 0, stream>>>(src, dst, H, packed, E, NB);
  fsort_k<<<NB, 256, 0, stream>>>(packed, H, esrc, rowp, N, E, NB);

  // ---- weight prep + x cast (chunked) ----
  prep_k<<<641, 256, 0, stream>>>(w_in, w_out, taps_w, taps_b,
                                  Wt_in, Wt_out, Wt_l0, Wt_l1, bsum);
  cast_f2b<<<castB, 256, 0, stream>>>(x, y1, N);

  // ---- readin: h = lrelu(x@Win+b); y0 = bf16(lrelu(h)) ----
  gemm_mfma<0, 128><<<gemmB, 256, 0, stream>>>(y1, y1, y1, y1, Wt_in, b_in, h, y0, 0, N);

  // ---- 2 residual graph-filter layers (cast fused into GEMM epilogue) ----
  int agg_i = 0;
  for (int l = 0; l < 2; l++) {
    const ushort* Wt_l = (l == 0) ? Wt_l0 : Wt_l1;
    agg_bf16<<<AGG_BLOCKS, 256, 0, stream>>>(y0, y1, rowp, esrc,
                                             cnts + 8 * CNT_STRIDE * agg_i++, N);
    agg_bf16<<<AGG_BLOCKS, 256, 0, stream>>>(y1, y2, rowp, esrc,
                                             cnts + 8 * CNT_STRIDE * agg_i++, N);
    agg_bf16<<<AGG_BLOCKS, 256, 0, stream>>>(y2, y3, rowp, esrc,
                                             cnts + 8 * CNT_STRIDE * agg_i++, N);
    gemm_mfma<1, 512><<<gemmB, 256, 0, stream>>>(y0, y1, y2, y3, Wt_l, bsum + l * 128,
                                                 h, y0, (l == 0) ? 1 : 0, N);
  }

  // ---- readout: d_out = h @ Wout + bout (reads y0 = bf16(h)) ----
  gemm_mfma<2, 128><<<gemmB, 256, 0, stream>>>(y0, y0, y0, y0, Wt_out, b_out,
                                               (float*)d_out, nullptr, 0, N);
}

// Round 9
// 451.176 us; speedup vs baseline: 2.3673x; 1.1161x over previous
//
#include <hip/hip_runtime.h>

typedef unsigned int uint;
typedef unsigned short ushort;

using bf16x8 = __attribute__((ext_vector_type(8))) short;
using f32x4  = __attribute__((ext_vector_type(4))) float;

__device__ __forceinline__ float lrelu(float v) { return v > 0.f ? v : 0.01f * v; }
__device__ __forceinline__ float b2f(ushort u) { return __uint_as_float((uint)u << 16); }
__device__ __forceinline__ ushort f2b(float f) {
  uint u = __float_as_uint(f);
  u += 0x7fffu + ((u >> 16) & 1u);   // round-to-nearest-even
  return (ushort)(u >> 16);
}

// HW_REG_XCC_ID = hwreg id 20 (gfx940+); size 32, offset 0 -> encoding (31<<11)|20.
__device__ __forceinline__ uint get_xcc() {
  return (uint)__builtin_amdgcn_s_getreg((31 << 11) | 20) & 7u;
}

#define CSR_B 256          // blocks in coarse passes
#define BKT_SHIFT 10       // 1024 dst nodes per bucket
#define MAX_NB 64          // max buckets (N <= 65536)
#define AGG_BLOCKS 2048    // agg grid (8/CU co-resident)
#define CNT_STRIDE 64      // ints between counters (256 B -> separate lines)

// y buffers: 4 chunks of 32 ch: y[chunk][node][32]. Row = 64 B = one cache
// line; chunk slab = 3.2 MB < 4 MiB per-XCD L2. R6 proved XCC pinning gives
// FETCH 175->18 MB; R7/R8 proved ANY cross-XCD counter traffic in the drain
// window costs 20-40 us. R9: census-based STATIC partition -- zero atomics in
// the agg hot path. census_k records (home XCD, ordinal) per blockIdx with one
// XCD-LOCAL atomicAdd; plan_k guarantees queue coverage under any placement.

// ---------------------------------------------------------------------------
// MFMA GEMM: C[N,128] = A[N,K] @ W[K,128] + bias, bf16 in / fp32 acc.
// ---------------------------------------------------------------------------
template <int MODE, int K>
__global__ __launch_bounds__(256) void gemm_mfma(
    const ushort* __restrict__ A0, const ushort* __restrict__ A1,
    const ushort* __restrict__ A2, const ushort* __restrict__ A3,
    const ushort* __restrict__ Wt, const float* __restrict__ bias,
    float* __restrict__ h, ushort* __restrict__ yout, int do_act, int N) {
  __shared__ ushort As[64][40];    // [m][k], stride 40 (16B-aligned, 2-way-free banks)
  __shared__ ushort Bs[128][40];   // [n][k]
  const int tid = threadIdx.x;
  const int lane = tid & 63;
  const int wave = tid >> 6;
  const int g = lane >> 4;         // k-quad
  const int mr = lane & 15;
  const int wr = wave >> 1;        // row half
  const int wc = wave & 1;         // col half
  const int row0 = blockIdx.x * 64;
  if (row0 >= N) return;           // grid may be padded to a multiple of 8

  const ushort* Ap[4] = {A0, A1, A2, A3};

  f32x4 acc[2][4];
#pragma unroll
  for (int i = 0; i < 2; i++)
#pragma unroll
    for (int j = 0; j < 4; j++) acc[i][j] = (f32x4){0.f, 0.f, 0.f, 0.f};

#pragma unroll 4
  for (int kc = 0; kc < K; kc += 32) {
    {  // stage A: 64 rows x 32 k (one uint4 per thread), 4x32-chunked layout
      int m = tid >> 2, q = tid & 3;
      int r = row0 + m;
      if (r >= N) r = N - 1;
      int kg = kc + q * 8;
      const ushort* ap = Ap[kg >> 7] + ((size_t)((kg >> 5) & 3)) * N * 32 +
                         (size_t)r * 32 + (kg & 31);
      *(uint4*)&As[m][q * 8] = *(const uint4*)ap;
    }
#pragma unroll
    for (int t = 0; t < 2; t++) {  // stage B: 128 n x 32 k
      int slot = tid + t * 256;
      int n = slot >> 2, q = slot & 3;
      *(uint4*)&Bs[n][q * 8] = *(const uint4*)(Wt + (size_t)n * K + kc + q * 8);
    }
    __syncthreads();
    bf16x8 af[2], bf[4];
#pragma unroll
    for (int rt = 0; rt < 2; rt++) af[rt] = *(bf16x8*)&As[wr * 32 + rt * 16 + mr][g * 8];
#pragma unroll
    for (int ct = 0; ct < 4; ct++) bf[ct] = *(bf16x8*)&Bs[wc * 64 + ct * 16 + mr][g * 8];
#pragma unroll
    for (int rt = 0; rt < 2; rt++)
#pragma unroll
      for (int ct = 0; ct < 4; ct++)
        acc[rt][ct] = __builtin_amdgcn_mfma_f32_16x16x32_bf16(af[rt], bf[ct], acc[rt][ct], 0, 0, 0);
    __syncthreads();
  }

  // epilogue: C/D layout col=lane&15, row=(lane>>4)*4+reg
#pragma unroll
  for (int rt = 0; rt < 2; rt++) {
#pragma unroll
    for (int i = 0; i < 4; i++) {
      int R = row0 + wr * 32 + rt * 16 + g * 4 + i;
      if (R >= N) continue;
#pragma unroll
      for (int ct = 0; ct < 4; ct++) {
        int c = wc * 64 + ct * 16 + mr;       // chunk = c>>5, within = c&31
        float v = acc[rt][ct][i] + bias[c];
        size_t o = (size_t)R * 128 + c;
        size_t oy = (size_t)(c >> 5) * N * 32 + (size_t)R * 32 + (c & 31);
        if (MODE == 0) {
          float hv = lrelu(v);
          h[o] = hv;
          yout[oy] = f2b(lrelu(hv));
        } else if (MODE == 1) {
          float hv = h[o] + v;
          h[o] = hv;
          if (yout) yout[oy] = f2b(do_act ? lrelu(hv) : hv);
        } else {
          h[o] = v;
        }
      }
    }
  }
}

// ---------------- census: record (home XCD, ordinal) per blockIdx ------------
// One XCD-LOCAL atomicAdd per block (counter line stays in that XCD's L2).
// s_sleep keeps blocks resident so placement mimics the long-running agg grid.
__global__ __launch_bounds__(256) void census_k(int* __restrict__ cnt8,
                                                int* __restrict__ home,
                                                int* __restrict__ ord) {
  if (threadIdx.x == 0) {
    uint h = get_xcc();
    int o = atomicAdd(&cnt8[h * CNT_STRIDE], 1);
    home[blockIdx.x] = (int)h;
    ord[blockIdx.x] = o;
  }
  __builtin_amdgcn_s_sleep(127);   // ~8k cycles: stay resident during dispatch
}

// ---------------- plan: owner[q] = q if XCD q got blocks, else fallback ------
__global__ __launch_bounds__(64) void plan_k(const int* __restrict__ cnt8,
                                             int* __restrict__ owner) {
  if (threadIdx.x == 0 && blockIdx.x == 0) {
    int fb = 0;
    for (int q = 0; q < 8; q++)
      if (cnt8[q * CNT_STRIDE] > 0) { fb = q; break; }
    for (int q = 0; q < 8; q++)
      owner[q] = (cnt8[q * CNT_STRIDE] > 0) ? q : fb;
  }
}

// ---------------- bf16 aggregation, census-static, zero atomics --------------
// Queue q (= chunk*? no: q = XCD id; chunk = q&3, half = q>>2) is processed by
// blocks whose census home h has owner[q]==h, tiles strided by census count.
__global__ __launch_bounds__(256) void agg_bf16(const ushort* __restrict__ yin,
                                                ushort* __restrict__ yout,
                                                const int* __restrict__ rowp,
                                                const ushort* __restrict__ esrc,
                                                const int* __restrict__ cnt8,
                                                const int* __restrict__ home,
                                                const int* __restrict__ ord,
                                                const int* __restrict__ owner,
                                                int N) {
  const int T = (N + 63) >> 6;    // 64-node tiles per chunk
  const int Th = (T + 1) >> 1;    // tiles per half
  const int b = blockIdx.x;
  const int h = home[b];
  const int o = ord[b];
  const int C = cnt8[h * CNT_STRIDE];
  const int t = threadIdx.x;
  const int lane = t & 3;
  const int nsub = t >> 2;

  for (int q = 0; q < 8; q++) {
    if (owner[q] != h) continue;
    const int chunk = q & 3;
    const int half = q >> 2;
    const int tbeg = half * Th;
    const int tcnt = min(T - tbeg, Th);
    if (tcnt <= 0) continue;
    const ushort* yb = yin + (size_t)chunk * N * 32 + lane * 8;
    ushort* yo = yout + (size_t)chunk * N * 32 + lane * 8;
    for (int rt = o; rt < tcnt; rt += C) {
      const int node = (tbeg + rt) * 64 + nsub;
      if (node >= N) continue;
      const int beg = rowp[node], end = rowp[node + 1];
      float s[8] = {0.f, 0.f, 0.f, 0.f, 0.f, 0.f, 0.f, 0.f};
      int j = beg;
      for (; j + 8 <= end; j += 8) {
        union { uint4 v; ushort u[8]; } w[8];
#pragma unroll
        for (int u = 0; u < 8; u++) {
          int sn = esrc[j + u];
          w[u].v = *(const uint4*)(yb + (size_t)sn * 32);
        }
#pragma unroll
        for (int e = 0; e < 8; e++) {
          float a = 0.f;
#pragma unroll
          for (int u = 0; u < 8; u++) a += b2f(w[u].u[e]);
          s[e] += a;
        }
      }
      for (; j < end; j++) {
        int sn = esrc[j];
        union { uint4 v; ushort u[8]; } w;
        w.v = *(const uint4*)(yb + (size_t)sn * 32);
#pragma unroll
        for (int e = 0; e < 8; e++) s[e] += b2f(w.u[e]);
      }
      union { uint4 v; ushort u[8]; } oo;
#pragma unroll
      for (int e = 0; e < 8; e++) oo.u[e] = f2b(s[e]);
      *(uint4*)(yo + (size_t)node * 32) = oo.v;
    }
  }
}

// ---------------- fp32 [N][128] -> bf16 chunked y ----------------
__global__ __launch_bounds__(256) void cast_f2b(const float* __restrict__ in,
                                                ushort* __restrict__ out, int N) {
  int i = blockIdx.x * 256 + threadIdx.x;
  if (i >= N * 16) return;
  int node = i >> 4, sub = i & 15;           // 8 channels per thread
  float4 a = *(const float4*)(in + (size_t)node * 128 + sub * 8);
  float4 b = *(const float4*)(in + (size_t)node * 128 + sub * 8 + 4);
  float v[8] = {a.x, a.y, a.z, a.w, b.x, b.y, b.z, b.w};
  union { uint4 q; ushort u[8]; } o;
#pragma unroll
  for (int e = 0; e < 8; e++) o.u[e] = f2b(v[e]);
  int chunk = sub >> 2, off = (sub & 3) * 8;
  *(uint4*)(out + (size_t)chunk * N * 32 + (size_t)node * 32 + off) = o.q;
}

// ---------------- weight prep: cast + transpose + bias sums ------------------
__global__ __launch_bounds__(256) void prep_k(const float* __restrict__ w_in,
                                              const float* __restrict__ w_out,
                                              const float* __restrict__ taps_w,
                                              const float* __restrict__ taps_b,
                                              ushort* __restrict__ Wt_in,
                                              ushort* __restrict__ Wt_out,
                                              ushort* __restrict__ Wt_l0,
                                              ushort* __restrict__ Wt_l1,
                                              float* __restrict__ bsum) {
  int gid = blockIdx.x * 256 + threadIdx.x;
  if (gid < 16384) {
    int n = gid >> 7, k = gid & 127;
    Wt_in[gid] = f2b(w_in[k * 128 + n]);
  } else if (gid < 32768) {
    int i = gid - 16384;
    int n = i >> 7, k = i & 127;
    Wt_out[i] = f2b(w_out[k * 128 + n]);
  } else if (gid < 98304) {
    int i = gid - 32768;
    int n = i >> 9, k = i & 511;
    Wt_l0[i] = f2b(taps_w[(size_t)k * 128 + n]);
  } else if (gid < 163840) {
    int i = gid - 98304;
    int n = i >> 9, k = i & 511;
    Wt_l1[i] = f2b(taps_w[(size_t)(512 + k) * 128 + n]);
  } else if (gid < 164096) {
    int i = gid - 163840;
    int l = i >> 7, n = i & 127;
    float s = 0.f;
    for (int k = 0; k < 4; k++) s += taps_b[l * 512 + k * 128 + n];
    bsum[i] = s;
  }
}

// ---------------- CSR build: 2-level binned counting sort --------------------
__global__ __launch_bounds__(256) void chist_k(const int* __restrict__ dst,
                                               int* __restrict__ H, int E, int NB) {
  __shared__ int hh[MAX_NB];
  if (threadIdx.x < NB) hh[threadIdx.x] = 0;
  __syncthreads();
  int chunk = (E + gridDim.x - 1) / gridDim.x;
  int beg = blockIdx.x * chunk, end = min(E, beg + chunk);
  for (int e = beg + threadIdx.x; e < end; e += 256)
    atomicAdd(&hh[dst[e] >> BKT_SHIFT], 1);
  __syncthreads();
  if (threadIdx.x < NB) H[threadIdx.x * gridDim.x + blockIdx.x] = hh[threadIdx.x];
}

__global__ __launch_bounds__(256) void cscan_k(int* __restrict__ H, int M) {
  __shared__ int sm[256];
  int per = (M + 255) / 256;
  int b0 = threadIdx.x * per;
  int hi = min(M, b0 + per);
  int sum = 0;
  for (int i = b0; i < hi; i++) sum += H[i];
  sm[threadIdx.x] = sum;
  __syncthreads();
  int x = sum;
  for (int off = 1; off < 256; off <<= 1) {
    int tt = (threadIdx.x >= off) ? sm[threadIdx.x - off] : 0;
    __syncthreads();
    x += tt;
    sm[threadIdx.x] = x;
    __syncthreads();
  }
  int run = x - sum;  // exclusive
  for (int i = b0; i < hi; i++) {
    int v = H[i];
    H[i] = run;
    run += v;
  }
}

__global__ __launch_bounds__(256) void cscatter_k(const int* __restrict__ src,
                                                  const int* __restrict__ dst,
                                                  const int* __restrict__ H,
                                                  uint* __restrict__ packed,
                                                  int E, int NB) {
  __shared__ int cur[MAX_NB];
  int chunk = (E + gridDim.x - 1) / gridDim.x;
  int beg = blockIdx.x * chunk, end = min(E, beg + chunk);
  if (threadIdx.x < NB) cur[threadIdx.x] = H[threadIdx.x * gridDim.x + blockIdx.x];
  __syncthreads();
  for (int e = beg + threadIdx.x; e < end; e += 256) {
    int d = dst[e];
    int pos = atomicAdd(&cur[d >> BKT_SHIFT], 1);
    packed[pos] = ((uint)d << 16) | (uint)src[e];
  }
}

__global__ __launch_bounds__(256) void fsort_k(const uint* __restrict__ packed,
                                               const int* __restrict__ H,
                                               ushort* __restrict__ esrc,
                                               int* __restrict__ rowp,
                                               int N, int E, int NB) {
  __shared__ int hist[1 << BKT_SHIFT];
  __shared__ int cur[1 << BKT_SHIFT];
  __shared__ int sm[256];
  const int bkt = blockIdx.x;
  const int base = bkt << BKT_SHIFT;
  const int nb_nodes = min(1 << BKT_SHIFT, N - base);
  const int start = H[bkt * CSR_B];
  const int end = (bkt == NB - 1) ? E : H[(bkt + 1) * CSR_B];

  for (int i = threadIdx.x; i < (1 << BKT_SHIFT); i += 256) hist[i] = 0;
  __syncthreads();
  for (int e = start + threadIdx.x; e < end; e += 256)
    atomicAdd(&hist[(packed[e] >> 16) - base], 1);
  __syncthreads();

  int t4 = threadIdx.x * 4;
  int l0 = hist[t4], l1 = hist[t4 + 1], l2 = hist[t4 + 2], l3 = hist[t4 + 3];
  int ssum = l0 + l1 + l2 + l3;
  sm[threadIdx.x] = ssum;
  __syncthreads();
  int x = ssum;
  for (int off = 1; off < 256; off <<= 1) {
    int tt = (threadIdx.x >= off) ? sm[threadIdx.x - off] : 0;
    __syncthreads();
    x += tt;
    sm[threadIdx.x] = x;
    __syncthreads();
  }
  int c0 = start + x - ssum;
  int c1 = c0 + l0, c2 = c1 + l1, c3 = c2 + l2;
  cur[t4] = c0; cur[t4 + 1] = c1; cur[t4 + 2] = c2; cur[t4 + 3] = c3;
  if (t4 + 0 < nb_nodes) rowp[base + t4 + 0] = c0;
  if (t4 + 1 < nb_nodes) rowp[base + t4 + 1] = c1;
  if (t4 + 2 < nb_nodes) rowp[base + t4 + 2] = c2;
  if (t4 + 3 < nb_nodes) rowp[base + t4 + 3] = c3;
  __syncthreads();

  for (int e = start + threadIdx.x; e < end; e += 256) {
    uint p = packed[e];
    int pos = atomicAdd(&cur[(p >> 16) - base], 1);
    esrc[pos] = (ushort)(p & 0xffffu);
  }
  if (bkt == 0 && threadIdx.x == 0) rowp[N] = E;
}

// ---------------------------------------------------------------------------
extern "C" void kernel_launch(void* const* d_in, const int* in_sizes, int n_in,
                              void* d_out, int out_size, void* d_ws, size_t ws_size,
                              hipStream_t stream) {
  const float* x      = (const float*)d_in[0];
  const int*   ei     = (const int*)d_in[1];
  const float* w_in   = (const float*)d_in[2];
  const float* b_in   = (const float*)d_in[3];
  const float* taps_w = (const float*)d_in[4];
  const float* taps_b = (const float*)d_in[5];
  const float* w_out  = (const float*)d_in[6];
  const float* b_out  = (const float*)d_in[7];

  const int N = in_sizes[0] / 128;
  const int E = in_sizes[1] / 2;
  const int* src = ei;
  const int* dst = ei + E;
  const int NB = (N + (1 << BKT_SHIFT) - 1) >> BKT_SHIFT;

  // h (fp32) lives in d_out until the readout GEMM overwrites it.
  float* h = (float*)d_out;

  // workspace (~57 MB)
  const size_t yelem = (size_t)N * 128;
  ushort* y0 = (ushort*)d_ws;
  ushort* y1 = y0 + yelem;
  ushort* y2 = y1 + yelem;
  ushort* y3 = y2 + yelem;
  ushort* Wt_in  = y3 + yelem;             // 128*128
  ushort* Wt_out = Wt_in + 128 * 128;      // 128*128
  ushort* Wt_l0  = Wt_out + 128 * 128;     // 128*512
  ushort* Wt_l1  = Wt_l0 + 128 * 512;      // 128*512
  float*  bsum   = (float*)(Wt_l1 + 128 * 512);   // 256
  int*    rowp   = (int*)(bsum + 256);     // N+1
  int*    H      = rowp + (N + 1);         // NB*CSR_B
  uint*   packed = (uint*)(H + MAX_NB * CSR_B);   // E
  ushort* esrc   = (ushort*)(packed + E);  // E
  int*    cnt8   = (int*)(esrc + E + (E & 1));    // 8 * CNT_STRIDE
  int*    owner  = cnt8 + 8 * CNT_STRIDE;         // 8
  int*    home   = owner + 8;                     // AGG_BLOCKS
  int*    ordb   = home + AGG_BLOCKS;             // AGG_BLOCKS

  const int gemmB = (N + 63) / 64;
  const int gemmBpad = ((gemmB + 7) / 8) * 8;     // keep dispatch count %8 == 0
  const int castB = (N * 16 + 255) / 256;

  // ---- zero census counters ----
  hipMemsetAsync(cnt8, 0, 8 * CNT_STRIDE * sizeof(int), stream);

  // ---- CSR build (binned counting sort) ----
  chist_k<<<CSR_B, 256, 0, stream>>>(dst, H, E, NB);
  cscan_k<<<1, 256, 0, stream>>>(H, NB * CSR_B);
  cscatter_k<<<CSR_B, 256, 0, stream>>>(src, dst, H, packed, E, NB);
  fsort_k<<<NB, 256, 0, stream>>>(packed, H, esrc, rowp, N, E, NB);

  // ---- weight prep + x cast (chunked) ----
  prep_k<<<641, 256, 0, stream>>>(w_in, w_out, taps_w, taps_b,
                                  Wt_in, Wt_out, Wt_l0, Wt_l1, bsum);
  cast_f2b<<<castB, 256, 0, stream>>>(x, y1, N);

  // ---- readin: h = lrelu(x@Win+b); y0 = bf16(lrelu(h)) ----
  gemm_mfma<0, 128><<<gemmB, 256, 0, stream>>>(y1, y1, y1, y1, Wt_in, b_in, h, y0, 0, N);

  // ---- census + plan (all later grids are multiples of 8 to preserve any
  //      round-robin alignment between census placement and agg placement) ----
  census_k<<<AGG_BLOCKS, 256, 0, stream>>>(cnt8, home, ordb);
  plan_k<<<8, 64, 0, stream>>>(cnt8, owner);

  // ---- 2 residual graph-filter layers (cast fused into GEMM epilogue) ----
  for (int l = 0; l < 2; l++) {
    const ushort* Wt_l = (l == 0) ? Wt_l0 : Wt_l1;
    agg_bf16<<<AGG_BLOCKS, 256, 0, stream>>>(y0, y1, rowp, esrc, cnt8, home, ordb, owner, N);
    agg_bf16<<<AGG_BLOCKS, 256, 0, stream>>>(y1, y2, rowp, esrc, cnt8, home, ordb, owner, N);
    agg_bf16<<<AGG_BLOCKS, 256, 0, stream>>>(y2, y3, rowp, esrc, cnt8, home, ordb, owner, N);
    gemm_mfma<1, 512><<<gemmBpad, 256, 0, stream>>>(y0, y1, y2, y3, Wt_l, bsum + l * 128,
                                                    h, y0, (l == 0) ? 1 : 0, N);
  }

  // ---- readout: d_out = h @ Wout + bout (reads y0 = bf16(h)) ----
  gemm_mfma<2, 128><<<gemmB, 256, 0, stream>>>(y0, y0, y0, y0, Wt_out, b_out,
                                               (float*)d_out, nullptr, 0, N);
}

// Round 10
// 414.374 us; speedup vs baseline: 2.5775x; 1.0888x over previous
//
#include <hip/hip_runtime.h>

typedef unsigned int uint;
typedef unsigned short ushort;

using bf16x8 = __attribute__((ext_vector_type(8))) short;
using f32x4  = __attribute__((ext_vector_type(4))) float;

__device__ __forceinline__ float lrelu(float v) { return v > 0.f ? v : 0.01f * v; }
__device__ __forceinline__ float b2f(ushort u) { return __uint_as_float((uint)u << 16); }
__device__ __forceinline__ ushort f2b(float f) {
  uint u = __float_as_uint(f);
  u += 0x7fffu + ((u >> 16) & 1u);   // round-to-nearest-even
  return (ushort)(u >> 16);
}

#define CSR_B 256          // blocks in coarse passes
#define BKT_SHIFT 10       // 1024 dst nodes per bucket
#define MAX_NB 64          // max buckets (N <= 65536)

// y buffers: 4 chunks of 32 ch: y[chunk][node][32]. Row = 64 B = one cache
// line (R5: no partial-line waste). R6-R9 verdict: XCD pinning works for
// locality (FETCH 175->18 MB) but every protocol variant loses more to
// counter traffic / placement mismatch than L2 locality recovers. Agg is
// locked at the R5 structure (~27 us, L3 random-line roofline).

// ---------------------------------------------------------------------------
// MFMA GEMM: C[N,128] = A[N,K] @ W[K,128] + bias, bf16 in / fp32 acc.
// 128x128 tile, 4 waves, each wave 64x64 = 4x4 MFMA(16x16x32) tiles.
// A given as up to 4 chunked y-buffer pointers (K = 128*buffers).
// Wt pre-transposed: Wt[n][k] bf16.
// MODE 0: h = lrelu(acc+b); yout = bf16(lrelu(h))           (readin)
// MODE 1: h += acc+b; if yout: yout = bf16(act? lrelu(h):h) (layer taps)
// MODE 2: h = acc+b                                          (readout)
// ---------------------------------------------------------------------------
template <int MODE, int K>
__global__ __launch_bounds__(256) void gemm_mfma(
    const ushort* __restrict__ A0, const ushort* __restrict__ A1,
    const ushort* __restrict__ A2, const ushort* __restrict__ A3,
    const ushort* __restrict__ Wt, const float* __restrict__ bias,
    float* __restrict__ h, ushort* __restrict__ yout, int do_act, int N) {
  __shared__ ushort As[128][40];   // [m][k], stride 40 (16B-aligned, 2-way-free banks)
  __shared__ ushort Bs[128][40];   // [n][k]
  const int tid = threadIdx.x;
  const int lane = tid & 63;
  const int wave = tid >> 6;
  const int g = lane >> 4;         // k-quad
  const int mr = lane & 15;
  const int wr = wave >> 1;        // row half (64 rows)
  const int wc = wave & 1;         // col half (64 cols)
  const int row0 = blockIdx.x * 128;
  if (row0 >= N) return;

  const ushort* Ap[4] = {A0, A1, A2, A3};

  f32x4 acc[4][4];
#pragma unroll
  for (int i = 0; i < 4; i++)
#pragma unroll
    for (int j = 0; j < 4; j++) acc[i][j] = (f32x4){0.f, 0.f, 0.f, 0.f};

#pragma unroll 2
  for (int kc = 0; kc < K; kc += 32) {
#pragma unroll
    for (int t2 = 0; t2 < 2; t2++) {  // stage A: 128 rows x 32 k
      int slot = tid + t2 * 256;
      int m = slot >> 2, q = slot & 3;
      int r = row0 + m;
      if (r >= N) r = N - 1;
      int kg = kc + q * 8;
      const ushort* ap = Ap[kg >> 7] + ((size_t)((kg >> 5) & 3)) * N * 32 +
                         (size_t)r * 32 + (kg & 31);
      *(uint4*)&As[m][q * 8] = *(const uint4*)ap;
    }
#pragma unroll
    for (int t2 = 0; t2 < 2; t2++) {  // stage B: 128 n x 32 k
      int slot = tid + t2 * 256;
      int n = slot >> 2, q = slot & 3;
      *(uint4*)&Bs[n][q * 8] = *(const uint4*)(Wt + (size_t)n * K + kc + q * 8);
    }
    __syncthreads();
    bf16x8 af[4], bf[4];
#pragma unroll
    for (int rt = 0; rt < 4; rt++) af[rt] = *(bf16x8*)&As[wr * 64 + rt * 16 + mr][g * 8];
#pragma unroll
    for (int ct = 0; ct < 4; ct++) bf[ct] = *(bf16x8*)&Bs[wc * 64 + ct * 16 + mr][g * 8];
#pragma unroll
    for (int rt = 0; rt < 4; rt++)
#pragma unroll
      for (int ct = 0; ct < 4; ct++)
        acc[rt][ct] = __builtin_amdgcn_mfma_f32_16x16x32_bf16(af[rt], bf[ct], acc[rt][ct], 0, 0, 0);
    __syncthreads();
  }

  // epilogue: C/D layout col=lane&15, row=(lane>>4)*4+reg
#pragma unroll
  for (int rt = 0; rt < 4; rt++) {
#pragma unroll
    for (int i = 0; i < 4; i++) {
      int R = row0 + wr * 64 + rt * 16 + g * 4 + i;
      if (R >= N) continue;
#pragma unroll
      for (int ct = 0; ct < 4; ct++) {
        int c = wc * 64 + ct * 16 + mr;       // chunk = c>>5, within = c&31
        float v = acc[rt][ct][i] + bias[c];
        size_t o = (size_t)R * 128 + c;
        size_t oy = (size_t)(c >> 5) * N * 32 + (size_t)R * 32 + (c & 31);
        if (MODE == 0) {
          float hv = lrelu(v);
          h[o] = hv;
          yout[oy] = f2b(lrelu(hv));
        } else if (MODE == 1) {
          float hv = h[o] + v;
          h[o] = hv;
          if (yout) yout[oy] = f2b(do_act ? lrelu(hv) : hv);
        } else {
          h[o] = v;
        }
      }
    }
  }
}

// ---------------- bf16 aggregation (R5 structure, proven fastest) ------------
// chunk = blockIdx&3; 4 lanes x uint4 (16 B) per node = one 64 B line per
// edge-gather; 64 nodes per block, 4-way unrolled gather.
__global__ __launch_bounds__(256) void agg_bf16(const ushort* __restrict__ yin,
                                                ushort* __restrict__ yout,
                                                const int* __restrict__ rowp,
                                                const ushort* __restrict__ esrc, int N) {
  int t = threadIdx.x;
  int chunk = blockIdx.x & 3;
  int node = (blockIdx.x >> 2) * 64 + (t >> 2);
  if (node >= N) return;
  int lane = t & 3;
  const ushort* yb = yin + (size_t)chunk * N * 32 + lane * 8;
  int beg = rowp[node], end = rowp[node + 1];
  float s[8] = {0.f, 0.f, 0.f, 0.f, 0.f, 0.f, 0.f, 0.f};
  int j = beg;
  for (; j + 4 <= end; j += 4) {
    int s0 = esrc[j], s1 = esrc[j + 1], s2 = esrc[j + 2], s3 = esrc[j + 3];
    union { uint4 v; ushort u[8]; } w0, w1, w2, w3;
    w0.v = *(const uint4*)(yb + (size_t)s0 * 32);
    w1.v = *(const uint4*)(yb + (size_t)s1 * 32);
    w2.v = *(const uint4*)(yb + (size_t)s2 * 32);
    w3.v = *(const uint4*)(yb + (size_t)s3 * 32);
#pragma unroll
    for (int e = 0; e < 8; e++)
      s[e] += (b2f(w0.u[e]) + b2f(w1.u[e])) + (b2f(w2.u[e]) + b2f(w3.u[e]));
  }
  for (; j < end; j++) {
    int sn = esrc[j];
    union { uint4 v; ushort u[8]; } w;
    w.v = *(const uint4*)(yb + (size_t)sn * 32);
#pragma unroll
    for (int e = 0; e < 8; e++) s[e] += b2f(w.u[e]);
  }
  union { uint4 v; ushort u[8]; } o;
#pragma unroll
  for (int e = 0; e < 8; e++) o.u[e] = f2b(s[e]);
  *(uint4*)(yout + (size_t)chunk * N * 32 + (size_t)node * 32 + lane * 8) = o.v;
}

// ---------------- fp32 [N][128] -> bf16 chunked y ----------------
__global__ __launch_bounds__(256) void cast_f2b(const float* __restrict__ in,
                                                ushort* __restrict__ out, int N) {
  int i = blockIdx.x * 256 + threadIdx.x;
  if (i >= N * 16) return;
  int node = i >> 4, sub = i & 15;           // 8 channels per thread
  float4 a = *(const float4*)(in + (size_t)node * 128 + sub * 8);
  float4 b = *(const float4*)(in + (size_t)node * 128 + sub * 8 + 4);
  float v[8] = {a.x, a.y, a.z, a.w, b.x, b.y, b.z, b.w};
  union { uint4 q; ushort u[8]; } o;
#pragma unroll
  for (int e = 0; e < 8; e++) o.u[e] = f2b(v[e]);
  int chunk = sub >> 2, off = (sub & 3) * 8;
  *(uint4*)(out + (size_t)chunk * N * 32 + (size_t)node * 32 + off) = o.q;
}

// ---------------- weight prep: cast + transpose + bias sums ------------------
__global__ __launch_bounds__(256) void prep_k(const float* __restrict__ w_in,
                                              const float* __restrict__ w_out,
                                              const float* __restrict__ taps_w,
                                              const float* __restrict__ taps_b,
                                              ushort* __restrict__ Wt_in,
                                              ushort* __restrict__ Wt_out,
                                              ushort* __restrict__ Wt_l0,
                                              ushort* __restrict__ Wt_l1,
                                              float* __restrict__ bsum) {
  int gid = blockIdx.x * 256 + threadIdx.x;
  if (gid < 16384) {
    int n = gid >> 7, k = gid & 127;
    Wt_in[gid] = f2b(w_in[k * 128 + n]);
  } else if (gid < 32768) {
    int i = gid - 16384;
    int n = i >> 7, k = i & 127;
    Wt_out[i] = f2b(w_out[k * 128 + n]);
  } else if (gid < 98304) {
    int i = gid - 32768;
    int n = i >> 9, k = i & 511;
    Wt_l0[i] = f2b(taps_w[(size_t)k * 128 + n]);
  } else if (gid < 163840) {
    int i = gid - 98304;
    int n = i >> 9, k = i & 511;
    Wt_l1[i] = f2b(taps_w[(size_t)(512 + k) * 128 + n]);
  } else if (gid < 164096) {
    int i = gid - 163840;
    int l = i >> 7, n = i & 127;
    float s = 0.f;
    for (int k = 0; k < 4; k++) s += taps_b[l * 512 + k * 128 + n];
    bsum[i] = s;
  }
}

// ---------------- CSR build: 2-level binned counting sort --------------------
__global__ __launch_bounds__(256) void chist_k(const int* __restrict__ dst,
                                               int* __restrict__ H, int E, int NB) {
  __shared__ int hh[MAX_NB];
  if (threadIdx.x < NB) hh[threadIdx.x] = 0;
  __syncthreads();
  int chunk = (E + gridDim.x - 1) / gridDim.x;
  int beg = blockIdx.x * chunk, end = min(E, beg + chunk);
  for (int e = beg + threadIdx.x; e < end; e += 256)
    atomicAdd(&hh[dst[e] >> BKT_SHIFT], 1);
  __syncthreads();
  if (threadIdx.x < NB) H[threadIdx.x * gridDim.x + blockIdx.x] = hh[threadIdx.x];
}

__global__ __launch_bounds__(256) void cscan_k(int* __restrict__ H, int M) {
  __shared__ int sm[256];
  int per = (M + 255) / 256;
  int b0 = threadIdx.x * per;
  int hi = min(M, b0 + per);
  int sum = 0;
  for (int i = b0; i < hi; i++) sum += H[i];
  sm[threadIdx.x] = sum;
  __syncthreads();
  int x = sum;
  for (int off = 1; off < 256; off <<= 1) {
    int tt = (threadIdx.x >= off) ? sm[threadIdx.x - off] : 0;
    __syncthreads();
    x += tt;
    sm[threadIdx.x] = x;
    __syncthreads();
  }
  int run = x - sum;  // exclusive
  for (int i = b0; i < hi; i++) {
    int v = H[i];
    H[i] = run;
    run += v;
  }
}

__global__ __launch_bounds__(256) void cscatter_k(const int* __restrict__ src,
                                                  const int* __restrict__ dst,
                                                  const int* __restrict__ H,
                                                  uint* __restrict__ packed,
                                                  int E, int NB) {
  __shared__ int cur[MAX_NB];
  int chunk = (E + gridDim.x - 1) / gridDim.x;
  int beg = blockIdx.x * chunk, end = min(E, beg + chunk);
  if (threadIdx.x < NB) cur[threadIdx.x] = H[threadIdx.x * gridDim.x + blockIdx.x];
  __syncthreads();
  for (int e = beg + threadIdx.x; e < end; e += 256) {
    int d = dst[e];
    int pos = atomicAdd(&cur[d >> BKT_SHIFT], 1);
    packed[pos] = ((uint)d << 16) | (uint)src[e];
  }
}

__global__ __launch_bounds__(256) void fsort_k(const uint* __restrict__ packed,
                                               const int* __restrict__ H,
                                               ushort* __restrict__ esrc,
                                               int* __restrict__ rowp,
                                               int N, int E, int NB) {
  __shared__ int hist[1 << BKT_SHIFT];
  __shared__ int cur[1 << BKT_SHIFT];
  __shared__ int sm[256];
  const int bkt = blockIdx.x;
  const int base = bkt << BKT_SHIFT;
  const int nb_nodes = min(1 << BKT_SHIFT, N - base);
  const int start = H[bkt * CSR_B];
  const int end = (bkt == NB - 1) ? E : H[(bkt + 1) * CSR_B];

  for (int i = threadIdx.x; i < (1 << BKT_SHIFT); i += 256) hist[i] = 0;
  __syncthreads();
  for (int e = start + threadIdx.x; e < end; e += 256)
    atomicAdd(&hist[(packed[e] >> 16) - base], 1);
  __syncthreads();

  int t4 = threadIdx.x * 4;
  int l0 = hist[t4], l1 = hist[t4 + 1], l2 = hist[t4 + 2], l3 = hist[t4 + 3];
  int ssum = l0 + l1 + l2 + l3;
  sm[threadIdx.x] = ssum;
  __syncthreads();
  int x = ssum;
  for (int off = 1; off < 256; off <<= 1) {
    int tt = (threadIdx.x >= off) ? sm[threadIdx.x - off] : 0;
    __syncthreads();
    x += tt;
    sm[threadIdx.x] = x;
    __syncthreads();
  }
  int c0 = start + x - ssum;
  int c1 = c0 + l0, c2 = c1 + l1, c3 = c2 + l2;
  cur[t4] = c0; cur[t4 + 1] = c1; cur[t4 + 2] = c2; cur[t4 + 3] = c3;
  if (t4 + 0 < nb_nodes) rowp[base + t4 + 0] = c0;
  if (t4 + 1 < nb_nodes) rowp[base + t4 + 1] = c1;
  if (t4 + 2 < nb_nodes) rowp[base + t4 + 2] = c2;
  if (t4 + 3 < nb_nodes) rowp[base + t4 + 3] = c3;
  __syncthreads();

  for (int e = start + threadIdx.x; e < end; e += 256) {
    uint p = packed[e];
    int pos = atomicAdd(&cur[(p >> 16) - base], 1);
    esrc[pos] = (ushort)(p & 0xffffu);
  }
  if (bkt == 0 && threadIdx.x == 0) rowp[N] = E;
}

// ---------------------------------------------------------------------------
extern "C" void kernel_launch(void* const* d_in, const int* in_sizes, int n_in,
                              void* d_out, int out_size, void* d_ws, size_t ws_size,
                              hipStream_t stream) {
  const float* x      = (const float*)d_in[0];
  const int*   ei     = (const int*)d_in[1];
  const float* w_in   = (const float*)d_in[2];
  const float* b_in   = (const float*)d_in[3];
  const float* taps_w = (const float*)d_in[4];
  const float* taps_b = (const float*)d_in[5];
  const float* w_out  = (const float*)d_in[6];
  const float* b_out  = (const float*)d_in[7];

  const int N = in_sizes[0] / 128;
  const int E = in_sizes[1] / 2;
  const int* src = ei;
  const int* dst = ei + E;
  const int NB = (N + (1 << BKT_SHIFT) - 1) >> BKT_SHIFT;

  // h (fp32) lives in d_out until the readout GEMM overwrites it.
  float* h = (float*)d_out;

  // workspace (~57 MB)
  const size_t yelem = (size_t)N * 128;
  ushort* y0 = (ushort*)d_ws;
  ushort* y1 = y0 + yelem;
  ushort* y2 = y1 + yelem;
  ushort* y3 = y2 + yelem;
  ushort* Wt_in  = y3 + yelem;             // 128*128
  ushort* Wt_out = Wt_in + 128 * 128;      // 128*128
  ushort* Wt_l0  = Wt_out + 128 * 128;     // 128*512
  ushort* Wt_l1  = Wt_l0 + 128 * 512;      // 128*512
  float*  bsum   = (float*)(Wt_l1 + 128 * 512);   // 256
  int*    rowp   = (int*)(bsum + 256);     // N+1
  int*    H      = rowp + (N + 1);         // NB*CSR_B
  uint*   packed = (uint*)(H + MAX_NB * CSR_B);   // E
  ushort* esrc   = (ushort*)(packed + E);  // E

  const int gemmB = (N + 127) / 128;
  const int aggB  = ((N + 63) / 64) * 4;   // node-blocks x 4 chunks
  const int castB = (N * 16 + 255) / 256;

  // ---- CSR build (binned counting sort) ----
  chist_k<<<CSR_B, 256, 0, stream>>>(dst, H, E, NB);
  cscan_k<<<1, 256, 0, stream>>>(H, NB * CSR_B);
  cscatter_k<<<CSR_B, 256, 0, stream>>>(src, dst, H, packed, E, NB);
  fsort_k<<<NB, 256, 0, stream>>>(packed, H, esrc, rowp, N, E, NB);

  // ---- weight prep + x cast (chunked) ----
  prep_k<<<641, 256, 0, stream>>>(w_in, w_out, taps_w, taps_b,
                                  Wt_in, Wt_out, Wt_l0, Wt_l1, bsum);
  cast_f2b<<<castB, 256, 0, stream>>>(x, y1, N);

  // ---- readin: h = lrelu(x@Win+b); y0 = bf16(lrelu(h)) ----
  gemm_mfma<0, 128><<<gemmB, 256, 0, stream>>>(y1, y1, y1, y1, Wt_in, b_in, h, y0, 0, N);

  // ---- 2 residual graph-filter layers (cast fused into GEMM epilogue) ----
  for (int l = 0; l < 2; l++) {
    const ushort* Wt_l = (l == 0) ? Wt_l0 : Wt_l1;
    agg_bf16<<<aggB, 256, 0, stream>>>(y0, y1, rowp, esrc, N);
    agg_bf16<<<aggB, 256, 0, stream>>>(y1, y2, rowp, esrc, N);
    agg_bf16<<<aggB, 256, 0, stream>>>(y2, y3, rowp, esrc, N);
    gemm_mfma<1, 512><<<gemmB, 256, 0, stream>>>(y0, y1, y2, y3, Wt_l, bsum + l * 128,
                                                 h, y0, (l == 0) ? 1 : 0, N);
  }

  // ---- readout: d_out = h @ Wout + bout (reads y0 = bf16(h)) ----
  gemm_mfma<2, 128><<<gemmB, 256, 0, stream>>>(y0, y0, y0, y0, Wt_out, b_out,
                                               (float*)d_out, nullptr, 0, N);
}